// Round 8
// baseline (152.377 us; speedup 1.0000x reference)
//
#include <hip/hip_runtime.h>
#include <cstdio>
#include <cmath>

#define TSEQ 2048
#define CDIM 1024
#define NBATCH 4

typedef float f32x4 __attribute__((ext_vector_type(4)));
typedef __bf16 bf16x8 __attribute__((ext_vector_type(8)));
typedef unsigned short u16;

// f32 -> bf16 round-to-nearest-even
__device__ __forceinline__ u16 f2bf(float f) {
  unsigned u = __builtin_bit_cast(unsigned, f);
  unsigned r = (u + 0x7FFFu + ((u >> 16) & 1u)) >> 16;
  return (u16)r;
}

// async global->LDS, 16B per lane; lds base wave-uniform (HW adds lane*16)
__device__ __forceinline__ void gload_lds16(const void* g, void* l) {
  __builtin_amdgcn_global_load_lds(
      (__attribute__((address_space(1))) void*)g,
      (__attribute__((address_space(3))) void*)l, 16, 0, 0);
}

// ---------------------------------------------------------------------------
// NEW qkv core: BM=128 x BN=256 x BK=32, 4 waves (2M x 2N), wave tile 64x128.
// ds_read:MFMA issue ratio 12 b128 : 32 MFMA = 0.375 (vs 0.5 at 64x64) AND
// 48 KiB LDS -> 2 blocks/CU TLP. LDS rows are 64 B (4 granules of 16B);
// granule swizzle g ^= (row&3)^((row>>2)&3) -> exactly 2-way bank alias
// (free, m136). Write side: linear gload_lds dest + inverse-permuted source
// granule. 6 gloads/K-tile; stage t+2 during tile t; vmcnt(6) per tile,
// vmcnt(0) at nT-2. nT even >= 2.
// ---------------------------------------------------------------------------
__device__ __forceinline__ void gemm128x256(
    const u16* __restrict__ A, const u16* __restrict__ B,
    int lda, int ldb, int m0, int n0, int nT,
    char* smem, f32x4 acc[4][8])
{
  u16* Ab = (u16*)smem;               // [2][128*32]
  u16* Bb = (u16*)(smem + 16384);     // [2][256*32]
  const int tid = threadIdx.x, w = tid >> 6, l = tid & 63;
  const int wr = w >> 1, wcB = w & 1;
  const int frow = l & 15, fko = l >> 4;
  const int swzr = (l & 3) ^ ((l >> 2) & 3);        // read-side swz(row)
  const int srow = l >> 2;                          // staging row (16/gload)
  const int sg = ((l & 3) ^ ((l >> 2) & 3) ^ ((l >> 4) & 3)) * 8;  // src col

  const u16* gA = A + (size_t)(m0 + w * 32 + srow) * lda + sg;
  const u16* gB = B + (size_t)(n0 + w * 64 + srow) * ldb + sg;

  auto stageA = [&](int t) {          // 128x32: 2 gloads/thread
    if (t >= nT) return;
    const u16* s = gA + t * 32;
    u16* d = Ab + (t & 1) * 4096 + w * 1024;
    gload_lds16(s, d);
    gload_lds16(s + (size_t)16 * lda, d + 512);
  };
  auto stageB = [&](int t) {          // 256x32: 4 gloads/thread
    if (t >= nT) return;
    const u16* s = gB + t * 32;
    u16* d = Bb + (t & 1) * 8192 + w * 2048;
    gload_lds16(s, d);
    gload_lds16(s + (size_t)16 * ldb, d + 512);
    gload_lds16(s + (size_t)32 * ldb, d + 1024);
    gload_lds16(s + (size_t)48 * ldb, d + 1536);
  };

  // byte offsets within current buffer; row stride 64 B
#define AOFF(mf) (((wr * 64 + (mf) * 16 + frow) * 64) + ((fko ^ swzr) * 16))
#define BOFF(nf) (((wcB * 128 + (nf) * 16 + frow) * 64) + ((fko ^ swzr) * 16))

  // prologue: tiles 0,1 staged (6 loads each)
  stageA(0); stageB(0); stageA(1); stageB(1);
  asm volatile("s_waitcnt vmcnt(6)" ::: "memory");
  __builtin_amdgcn_s_barrier();

#pragma unroll 1
  for (int t = 0; t < nT; ++t) {
    const char* Abase = (const char*)Ab + (t & 1) * 8192;
    const char* Bbase = (const char*)Bb + (t & 1) * 16384;
    // ---- phase 0: A-frags (all 4) + B-frags nf 0..3; stage A(t+2)
    bf16x8 af[4], bf0[4];
#pragma unroll
    for (int mf = 0; mf < 4; ++mf)
      af[mf] = *(const bf16x8*)(Abase + AOFF(mf));
#pragma unroll
    for (int nf = 0; nf < 4; ++nf)
      bf0[nf] = *(const bf16x8*)(Bbase + BOFF(nf));
    __builtin_amdgcn_sched_barrier(0);
    stageA(t + 2);
    __builtin_amdgcn_s_barrier();
    __builtin_amdgcn_s_setprio(1);
#pragma unroll
    for (int mf = 0; mf < 4; ++mf)
#pragma unroll
      for (int nf = 0; nf < 4; ++nf)
        acc[mf][nf] = __builtin_amdgcn_mfma_f32_16x16x32_bf16(
            af[mf], bf0[nf], acc[mf][nf], 0, 0, 0);
    __builtin_amdgcn_s_setprio(0);
    __builtin_amdgcn_s_barrier();
    // ---- phase 1: B-frags nf 4..7; stage B(t+2)
    bf16x8 bf1[4];
#pragma unroll
    for (int nf = 0; nf < 4; ++nf)
      bf1[nf] = *(const bf16x8*)(Bbase + BOFF(4 + nf));
    __builtin_amdgcn_sched_barrier(0);
    stageB(t + 2);
    __builtin_amdgcn_s_barrier();
    __builtin_amdgcn_s_setprio(1);
#pragma unroll
    for (int mf = 0; mf < 4; ++mf)
#pragma unroll
      for (int nf = 0; nf < 4; ++nf)
        acc[mf][4 + nf] = __builtin_amdgcn_mfma_f32_16x16x32_bf16(
            af[mf], bf1[nf], acc[mf][4 + nf], 0, 0, 0);
    __builtin_amdgcn_s_setprio(0);
    if (t < nT - 2) asm volatile("s_waitcnt vmcnt(6)" ::: "memory");
    else if (t == nT - 2) asm volatile("s_waitcnt vmcnt(0)" ::: "memory");
    __builtin_amdgcn_s_barrier();
  }
#undef AOFF
#undef BOFF
}

// ---------------------------------------------------------------------------
// R7 4-wave 128x128 BK=64 core (scores/pv — unchanged this round)
// ---------------------------------------------------------------------------
#define SWZ2(b_) ((b_) ^ ((((b_) >> 7) & 7) << 4))

__device__ __forceinline__ void gemm128(
    const u16* __restrict__ A, const u16* __restrict__ B,
    int lda, int ldb, int m0, int n0, int nT,
    char* smem, f32x4 acc[4][4])
{
  u16* Ab = (u16*)smem;               // [2][128*64]
  u16* Bb = (u16*)(smem + 32768);     // [2][128*64]
  const int tid = threadIdx.x, w = tid >> 6, l = tid & 63;
  const int wr = w >> 1, wc = w & 1;
  const int frow = l & 15, fko = l >> 4;
  const int srow = l >> 3;
  const int scol = ((l & 7) * 8) ^ (((l >> 3) & 7) << 3);

  const u16* gA = A + (size_t)(m0 + w * 32 + srow) * lda + scol;
  const u16* gB = B + (size_t)(n0 + w * 32 + srow) * ldb + scol;

  auto stageA = [&](int t) {
    if (t >= nT) return;
    const u16* s = gA + t * 64;
    u16* d = Ab + (t & 1) * 8192 + w * 2048;
    gload_lds16(s, d);
    gload_lds16(s + (size_t)8 * lda, d + 512);
    gload_lds16(s + (size_t)16 * lda, d + 1024);
    gload_lds16(s + (size_t)24 * lda, d + 1536);
  };
  auto stageB = [&](int t) {
    if (t >= nT) return;
    const u16* s = gB + t * 64;
    u16* d = Bb + (t & 1) * 8192 + w * 2048;
    gload_lds16(s, d);
    gload_lds16(s + (size_t)8 * ldb, d + 512);
    gload_lds16(s + (size_t)16 * ldb, d + 1024);
    gload_lds16(s + (size_t)24 * ldb, d + 1536);
  };

#define AOFF(mf, ks) SWZ2(((wr * 64 + (mf) * 16 + frow) * 128 + (ks) * 64 + fko * 16))
#define BOFF(nf, ks) SWZ2(((wc * 64 + (nf) * 16 + frow) * 128 + (ks) * 64 + fko * 16))

  stageB(0); stageA(0); stageB(1); stageA(1);
  asm volatile("s_waitcnt vmcnt(8)" ::: "memory");
  __builtin_amdgcn_s_barrier();

#pragma unroll 1
  for (int t = 0; t < nT; ++t) {
    const char* Abase = (const char*)Ab + (t & 1) * 16384;
    const char* Bbase = (const char*)Bb + (t & 1) * 16384;
    bf16x8 bfr[4][2], af0[2][2];
#pragma unroll
    for (int nf = 0; nf < 4; ++nf)
#pragma unroll
      for (int ks = 0; ks < 2; ++ks)
        bfr[nf][ks] = *(const bf16x8*)(Bbase + BOFF(nf, ks));
#pragma unroll
    for (int mm = 0; mm < 2; ++mm)
#pragma unroll
      for (int ks = 0; ks < 2; ++ks)
        af0[mm][ks] = *(const bf16x8*)(Abase + AOFF(mm, ks));
    __builtin_amdgcn_sched_barrier(0);
    stageB(t + 2);
    __builtin_amdgcn_s_barrier();
    __builtin_amdgcn_s_setprio(1);
#pragma unroll
    for (int ks = 0; ks < 2; ++ks)
#pragma unroll
      for (int mm = 0; mm < 2; ++mm)
#pragma unroll
        for (int nf = 0; nf < 4; ++nf)
          acc[mm][nf] = __builtin_amdgcn_mfma_f32_16x16x32_bf16(
              af0[mm][ks], bfr[nf][ks], acc[mm][nf], 0, 0, 0);
    __builtin_amdgcn_s_setprio(0);
    __builtin_amdgcn_s_barrier();
    bf16x8 af1[2][2];
#pragma unroll
    for (int mm = 0; mm < 2; ++mm)
#pragma unroll
      for (int ks = 0; ks < 2; ++ks)
        af1[mm][ks] = *(const bf16x8*)(Abase + AOFF(2 + mm, ks));
    __builtin_amdgcn_sched_barrier(0);
    stageA(t + 2);
    __builtin_amdgcn_s_barrier();
    __builtin_amdgcn_s_setprio(1);
#pragma unroll
    for (int ks = 0; ks < 2; ++ks)
#pragma unroll
      for (int mm = 0; mm < 2; ++mm)
#pragma unroll
        for (int nf = 0; nf < 4; ++nf)
          acc[2 + mm][nf] = __builtin_amdgcn_mfma_f32_16x16x32_bf16(
              af1[mm][ks], bfr[nf][ks], acc[2 + mm][nf], 0, 0, 0);
    __builtin_amdgcn_s_setprio(0);
    if (t < nT - 2) asm volatile("s_waitcnt vmcnt(8)" ::: "memory");
    else if (t == nT - 2) asm volatile("s_waitcnt vmcnt(0)" ::: "memory");
    __builtin_amdgcn_s_barrier();
  }
#undef AOFF
#undef BOFF
}

#define ACC_ZERO4(acc)                                  \
  _Pragma("unroll") for (int m_ = 0; m_ < 4; ++m_)      \
  _Pragma("unroll") for (int n_ = 0; n_ < 4; ++n_)      \
      acc[m_][n_] = (f32x4){0.f, 0.f, 0.f, 0.f};

// ---------------------------------------------------------------------------
// single cvt kernel for x, Wk, Wq, Wv
__global__ void __launch_bounds__(256) k_cvt_all(
    const float* __restrict__ x, const float* __restrict__ Wk,
    const float* __restrict__ Wq, const float* __restrict__ Wv,
    u16* __restrict__ xb, u16* __restrict__ wb)
{
  const int NX4 = (NBATCH * TSEQ * CDIM) / 4;
  const int NW4 = (CDIM * CDIM) / 4;
  int g = blockIdx.x * 256 + threadIdx.x;
  const float* src; u16* dst; int i;
  if (g < NX4) { src = x; dst = xb; i = g; }
  else {
    int g2 = g - NX4;
    int w = g2 / NW4; i = g2 - w * NW4;
    src = (w == 0) ? Wk : (w == 1) ? Wq : Wv;
    dst = wb + (size_t)w * CDIM * CDIM;
  }
  float4 v = ((const float4*)src)[i];
  ushort4 o;
  o.x = f2bf(v.x); o.y = f2bf(v.y); o.z = f2bf(v.z); o.w = f2bf(v.w);
  ((ushort4*)dst)[i] = o;
}

// ---------------------------------------------------------------------------
// QKV: A = xb [8192][1024], B = wb [3072][1024]. 768 blocks = 8 XCD x 96
// = 3.0 exact rounds. Per XCD 8 m-panels (2MB L2-resident); nt slow.
__global__ void __launch_bounds__(256, 2) k_gemm_qkv_t(
    const u16* __restrict__ xb, const u16* __restrict__ wb,
    u16* __restrict__ kb, u16* __restrict__ qb, u16* __restrict__ vb)
{
  extern __shared__ char smem[];
  const int id = blockIdx.x;
  const int xcd = id & 7, loc = id >> 3;
  const int mt = xcd * 8 + (loc & 7);        // 0..63
  const int nt = loc >> 3;                   // 0..11
  const int m0 = mt * 128, n0g = nt * 256;

  f32x4 acc[4][8];
#pragma unroll
  for (int m_ = 0; m_ < 4; ++m_)
#pragma unroll
    for (int n_ = 0; n_ < 8; ++n_) acc[m_][n_] = (f32x4){0.f, 0.f, 0.f, 0.f};

  gemm128x256(xb, wb, CDIM, CDIM, m0, n0g, 32, smem, acc);

  const int tid = threadIdx.x, w = tid >> 6, l = tid & 63;
  const int wr = w >> 1, wcB = w & 1;
  const int frow = l & 15, fko = l >> 4;
  const int z = n0g >> 10;
  u16* outp = (z == 0) ? kb : (z == 1) ? qb : vb;
  const float scale = (z == 1) ? 0.03125f : 1.0f;
  const int r0 = m0 + wr * 64 + fko * 4;
  const int c0 = (n0g & 1023) + wcB * 128 + frow;
#pragma unroll
  for (int mf = 0; mf < 4; ++mf)
#pragma unroll
    for (int nf = 0; nf < 8; ++nf) {
      const int r = r0 + mf * 16;
      const int c = c0 + nf * 16;
#pragma unroll
      for (int j = 0; j < 4; ++j)
        outp[(size_t)(r + j) * CDIM + c] = f2bf(acc[mf][nf][j] * scale);
    }
}

// ---------------------------------------------------------------------------
// Scores: S = Q K^T -> P_unnorm = exp(S) bf16 (max-free) + rowsum partials.
__global__ void __launch_bounds__(256, 2) k_gemm_scores_t(
    const u16* __restrict__ qb, const u16* __restrict__ kb,
    u16* __restrict__ pb, float* __restrict__ rs)
{
  extern __shared__ char smem[];
  const int id = blockIdx.x;
  const int sw = (id & 7) * 68 + (id >> 3);
  const int b = sw / 136;
  const int wq = sw - b * 136;
  int y = (int)((sqrtf(8.f * wq + 1.f) - 1.f) * 0.5f);
  while ((y + 1) * (y + 2) / 2 <= wq) ++y;
  while (y * (y + 1) / 2 > wq) --y;
  const int xt = wq - y * (y + 1) / 2;
  const int m0 = y * 128, n0 = xt * 128;

  const u16* A = qb + (size_t)b * TSEQ * CDIM;
  const u16* B = kb + (size_t)b * TSEQ * CDIM;
  u16* P = pb + (size_t)b * TSEQ * TSEQ;

  f32x4 acc[4][4];
  ACC_ZERO4(acc);
  gemm128(A, B, CDIM, CDIM, m0, n0, 16, smem, acc);

  const int tid = threadIdx.x, w = tid >> 6, l = tid & 63;
  const int wr = w >> 1, wc = w & 1;
  const int frow = l & 15, fko = l >> 4;
  float* rowpart = (float*)smem;

#pragma unroll
  for (int mf = 0; mf < 4; ++mf) {
#pragma unroll
    for (int j = 0; j < 4; ++j) {
      const int rloc = wr * 64 + mf * 16 + fko * 4 + j;
      const int rglob = m0 + rloc;
      float p4 = 0.f;
#pragma unroll
      for (int nf = 0; nf < 4; ++nf) {
        const int c = n0 + wc * 64 + nf * 16 + frow;
        float e = (c <= rglob) ? __expf(acc[mf][nf][j]) : 0.f;
        p4 += e;
        P[(size_t)rglob * TSEQ + c] = f2bf(e);
      }
#pragma unroll
      for (int d = 1; d < 16; d <<= 1) p4 += __shfl_xor(p4, d);
      if (frow == 0) rowpart[rloc * 2 + wc] = p4;
    }
  }
  __syncthreads();
  if (tid < 128)
    rs[((size_t)b * 16 + xt) * TSEQ + m0 + tid] =
        rowpart[tid * 2] + rowpart[tid * 2 + 1];
}

// ---------------------------------------------------------------------------
// V[2048][1024] -> Vt[1024][2048] per batch
__global__ void __launch_bounds__(256) k_transpose_v(const u16* __restrict__ vb,
                                                     u16* __restrict__ vt) {
  __shared__ u16 tile[32][33];
  const int b = blockIdx.z;
  const u16* V = vb + (size_t)b * TSEQ * CDIM;
  u16* Vt = vt + (size_t)b * CDIM * TSEQ;
  const int c0 = blockIdx.x * 32, r0 = blockIdx.y * 32;
  const int tx = threadIdx.x, ty = threadIdx.y;
#pragma unroll
  for (int j = 0; j < 4; ++j)
    tile[ty + j * 8][tx] = V[(size_t)(r0 + ty + j * 8) * CDIM + c0 + tx];
  __syncthreads();
#pragma unroll
  for (int j = 0; j < 4; ++j)
    Vt[(size_t)(c0 + ty + j * 8) * TSEQ + r0 + tx] = tile[tx][ty + j * 8];
}

// inv_rowsum[b][t] = 1 / sum_{x<=ytile} rs[b][x][t]
__global__ void __launch_bounds__(256) k_suminv(const float* __restrict__ rs,
                                                float* __restrict__ inv) {
  const int i = blockIdx.x * 256 + threadIdx.x;
  const int b = i >> 11, t = i & (TSEQ - 1), y = t >> 7;
  const float* p = rs + (size_t)b * 16 * TSEQ + t;
  float s = 0.f;
  for (int x = 0; x <= y; ++x) s += p[(size_t)x * TSEQ];
  inv[i] = 1.f / s;
}

// ---------------------------------------------------------------------------
// O = (P_unnorm @ V) * inv_rowsum; causal K-extent nT = 2*(mt+1).
__global__ void __launch_bounds__(256, 2) k_gemm_pv_t(
    const u16* __restrict__ pb, const u16* __restrict__ vt,
    const float* __restrict__ inv, float* __restrict__ out)
{
  extern __shared__ char smem[];
  const int id = blockIdx.x;
  const int n = id & 7, loc = id >> 3;
  const int b = loc >> 4, mt = loc & 15;
  const int m0 = mt * 128, n0 = n * 128;
  const int nT = 2 * (mt + 1);

  const u16* A = pb + (size_t)b * TSEQ * TSEQ;
  const u16* B = vt + (size_t)b * CDIM * TSEQ;
  float* O = out + (size_t)b * TSEQ * CDIM;

  f32x4 acc[4][4];
  ACC_ZERO4(acc);
  gemm128(A, B, TSEQ, TSEQ, m0, n0, nT, smem, acc);

  const int tid = threadIdx.x, w = tid >> 6, l = tid & 63;
  const int wr = w >> 1, wc = w & 1;
  const int frow = l & 15, fko = l >> 4;
#pragma unroll
  for (int mf = 0; mf < 4; ++mf) {
    const int r = m0 + wr * 64 + mf * 16 + fko * 4;
    const float4 iv = *(const float4*)&inv[(size_t)b * TSEQ + r];
    const float ivj[4] = {iv.x, iv.y, iv.z, iv.w};
#pragma unroll
    for (int nf = 0; nf < 4; ++nf) {
      const int c = n0 + wc * 64 + nf * 16 + frow;
#pragma unroll
      for (int j = 0; j < 4; ++j)
        O[(size_t)(r + j) * CDIM + c] = acc[mf][nf][j] * ivj[j];
    }
  }
}

// ---------------------------------------------------------------------------
extern "C" void kernel_launch(void* const* d_in, const int* in_sizes, int n_in,
                              void* d_out, int out_size, void* d_ws, size_t ws_size,
                              hipStream_t stream) {
  const float* x  = (const float*)d_in[0];
  const float* Wk = (const float*)d_in[1];
  const float* Wq = (const float*)d_in[2];
  const float* Wv = (const float*)d_in[3];
  float* out = (float*)d_out;

  const size_t M = (size_t)NBATCH * TSEQ;

  size_t off = 0;
  auto alloc = [&](size_t bytes) {
    void* p = (char*)d_ws + off;
    off += (bytes + 255) & ~(size_t)255;
    return p;
  };
  u16* xb = (u16*)alloc(M * CDIM * 2);
  u16* wb = (u16*)alloc(3ull * CDIM * CDIM * 2);
  u16* qb = (u16*)alloc(M * CDIM * 2);
  u16* kb = (u16*)alloc(M * CDIM * 2);
  u16* vb = (u16*)alloc(M * CDIM * 2);
  u16* pbuf = (u16*)alloc((size_t)NBATCH * TSEQ * TSEQ * 2);
  float* rs  = (float*)alloc((size_t)NBATCH * 16 * TSEQ * 4);
  float* inv = (float*)alloc(M * 4);
  if (off > ws_size) {
    fprintf(stderr, "kernel_launch: ws too small: need %zu, have %zu\n", off, ws_size);
    return;
  }
  u16* vt = xb;  // Vt overlay (x dead after QKV)

  const int NX4 = (NBATCH * TSEQ * CDIM) / 4;
  const int NW4 = (CDIM * CDIM) / 4;
  const int cvtBlocks = (NX4 + 3 * NW4) / 256;

  static_cast<void>(hipFuncSetAttribute(
      reinterpret_cast<const void*>(k_gemm_qkv_t),
      hipFuncAttributeMaxDynamicSharedMemorySize, 49152));
  static_cast<void>(hipFuncSetAttribute(
      reinterpret_cast<const void*>(k_gemm_scores_t),
      hipFuncAttributeMaxDynamicSharedMemorySize, 65536));
  static_cast<void>(hipFuncSetAttribute(
      reinterpret_cast<const void*>(k_gemm_pv_t),
      hipFuncAttributeMaxDynamicSharedMemorySize, 65536));

  k_cvt_all<<<cvtBlocks, 256, 0, stream>>>(x, Wk, Wq, Wv, xb, wb);
  k_gemm_qkv_t<<<768, 256, 49152, stream>>>(xb, wb, kb, qb, vb);
  k_transpose_v<<<dim3(CDIM / 32, TSEQ / 32, NBATCH), dim3(32, 8), 0, stream>>>(vb, vt);
  k_gemm_scores_t<<<544, 256, 65536, stream>>>(qb, kb, pbuf, rs);
  k_suminv<<<(int)(M / 256), 256, 0, stream>>>(rs, inv);
  k_gemm_pv_t<<<512, 256, 65536, stream>>>(pbuf, vt, inv, out);
}

// Round 9
// 139.538 us; speedup vs baseline: 1.0920x; 1.0920x over previous
//
#include <hip/hip_runtime.h>
#include <cstdio>
#include <cmath>

#define TSEQ 2048
#define CDIM 1024
#define NBATCH 4

typedef float f32x4 __attribute__((ext_vector_type(4)));
typedef __bf16 bf16x8 __attribute__((ext_vector_type(8)));
typedef unsigned short u16;

// f32 -> bf16 round-to-nearest-even
__device__ __forceinline__ u16 f2bf(float f) {
  unsigned u = __builtin_bit_cast(unsigned, f);
  unsigned r = (u + 0x7FFFu + ((u >> 16) & 1u)) >> 16;
  return (u16)r;
}

// async global->LDS, 16B per lane; lds base wave-uniform (HW adds lane*16)
__device__ __forceinline__ void gload_lds16(const void* g, void* l) {
  __builtin_amdgcn_global_load_lds(
      (__attribute__((address_space(1))) void*)g,
      (__attribute__((address_space(3))) void*)l, 16, 0, 0);
}

// ---------------------------------------------------------------------------
// R7 4-wave 128x128 BK=64 core (proven: 0 bank conflicts, 2 blocks/CU TLP).
// D[m,n] = sum_k A[m,k]*B[n,k], K-major bf16. 256 thr = 4 waves (2M x 2N),
// wave tile 64x64 = acc[4][4] of 16x16x32 MFMA. LDS 64 KiB.
// T2 full 3-bit XOR swizzle; stage t+2 during tile t; vmcnt(8)/vmcnt(0).
// nT even >= 2.
// ---------------------------------------------------------------------------
#define SWZ2(b_) ((b_) ^ ((((b_) >> 7) & 7) << 4))

__device__ __forceinline__ void gemm128(
    const u16* __restrict__ A, const u16* __restrict__ B,
    int lda, int ldb, int m0, int n0, int nT,
    char* smem, f32x4 acc[4][4])
{
  u16* Ab = (u16*)smem;               // [2][128*64]
  u16* Bb = (u16*)(smem + 32768);     // [2][128*64]
  const int tid = threadIdx.x, w = tid >> 6, l = tid & 63;
  const int wr = w >> 1, wc = w & 1;
  const int frow = l & 15, fko = l >> 4;
  const int srow = l >> 3;
  const int scol = ((l & 7) * 8) ^ (((l >> 3) & 7) << 3);

  const u16* gA = A + (size_t)(m0 + w * 32 + srow) * lda + scol;
  const u16* gB = B + (size_t)(n0 + w * 32 + srow) * ldb + scol;

  auto stageA = [&](int t) {
    if (t >= nT) return;
    const u16* s = gA + t * 64;
    u16* d = Ab + (t & 1) * 8192 + w * 2048;
    gload_lds16(s, d);
    gload_lds16(s + (size_t)8 * lda, d + 512);
    gload_lds16(s + (size_t)16 * lda, d + 1024);
    gload_lds16(s + (size_t)24 * lda, d + 1536);
  };
  auto stageB = [&](int t) {
    if (t >= nT) return;
    const u16* s = gB + t * 64;
    u16* d = Bb + (t & 1) * 8192 + w * 2048;
    gload_lds16(s, d);
    gload_lds16(s + (size_t)8 * ldb, d + 512);
    gload_lds16(s + (size_t)16 * ldb, d + 1024);
    gload_lds16(s + (size_t)24 * ldb, d + 1536);
  };

#define AOFF(mf, ks) SWZ2(((wr * 64 + (mf) * 16 + frow) * 128 + (ks) * 64 + fko * 16))
#define BOFF(nf, ks) SWZ2(((wc * 64 + (nf) * 16 + frow) * 128 + (ks) * 64 + fko * 16))

  stageB(0); stageA(0); stageB(1); stageA(1);
  asm volatile("s_waitcnt vmcnt(8)" ::: "memory");
  __builtin_amdgcn_s_barrier();

#pragma unroll 1
  for (int t = 0; t < nT; ++t) {
    const char* Abase = (const char*)Ab + (t & 1) * 16384;
    const char* Bbase = (const char*)Bb + (t & 1) * 16384;
    bf16x8 bfr[4][2], af0[2][2];
#pragma unroll
    for (int nf = 0; nf < 4; ++nf)
#pragma unroll
      for (int ks = 0; ks < 2; ++ks)
        bfr[nf][ks] = *(const bf16x8*)(Bbase + BOFF(nf, ks));
#pragma unroll
    for (int mm = 0; mm < 2; ++mm)
#pragma unroll
      for (int ks = 0; ks < 2; ++ks)
        af0[mm][ks] = *(const bf16x8*)(Abase + AOFF(mm, ks));
    __builtin_amdgcn_sched_barrier(0);
    stageB(t + 2);
    __builtin_amdgcn_s_barrier();
    __builtin_amdgcn_s_setprio(1);
#pragma unroll
    for (int ks = 0; ks < 2; ++ks)
#pragma unroll
      for (int mm = 0; mm < 2; ++mm)
#pragma unroll
        for (int nf = 0; nf < 4; ++nf)
          acc[mm][nf] = __builtin_amdgcn_mfma_f32_16x16x32_bf16(
              af0[mm][ks], bfr[nf][ks], acc[mm][nf], 0, 0, 0);
    __builtin_amdgcn_s_setprio(0);
    __builtin_amdgcn_s_barrier();
    bf16x8 af1[2][2];
#pragma unroll
    for (int mm = 0; mm < 2; ++mm)
#pragma unroll
      for (int ks = 0; ks < 2; ++ks)
        af1[mm][ks] = *(const bf16x8*)(Abase + AOFF(2 + mm, ks));
    __builtin_amdgcn_sched_barrier(0);
    stageA(t + 2);
    __builtin_amdgcn_s_barrier();
    __builtin_amdgcn_s_setprio(1);
#pragma unroll
    for (int ks = 0; ks < 2; ++ks)
#pragma unroll
      for (int mm = 0; mm < 2; ++mm)
#pragma unroll
        for (int nf = 0; nf < 4; ++nf)
          acc[2 + mm][nf] = __builtin_amdgcn_mfma_f32_16x16x32_bf16(
              af1[mm][ks], bfr[nf][ks], acc[2 + mm][nf], 0, 0, 0);
    __builtin_amdgcn_s_setprio(0);
    if (t < nT - 2) asm volatile("s_waitcnt vmcnt(8)" ::: "memory");
    else if (t == nT - 2) asm volatile("s_waitcnt vmcnt(0)" ::: "memory");
    __builtin_amdgcn_s_barrier();
  }
#undef AOFF
#undef BOFF
}

#define ACC_ZERO4(acc)                                  \
  _Pragma("unroll") for (int m_ = 0; m_ < 4; ++m_)      \
  _Pragma("unroll") for (int n_ = 0; n_ < 4; ++n_)      \
      acc[m_][n_] = (f32x4){0.f, 0.f, 0.f, 0.f};

// ---------------------------------------------------------------------------
// single cvt kernel for x, Wk, Wq, Wv
__global__ void __launch_bounds__(256) k_cvt_all(
    const float* __restrict__ x, const float* __restrict__ Wk,
    const float* __restrict__ Wq, const float* __restrict__ Wv,
    u16* __restrict__ xb, u16* __restrict__ wb)
{
  const int NX4 = (NBATCH * TSEQ * CDIM) / 4;
  const int NW4 = (CDIM * CDIM) / 4;
  int g = blockIdx.x * 256 + threadIdx.x;
  const float* src; u16* dst; int i;
  if (g < NX4) { src = x; dst = xb; i = g; }
  else {
    int g2 = g - NX4;
    int w = g2 / NW4; i = g2 - w * NW4;
    src = (w == 0) ? Wk : (w == 1) ? Wq : Wv;
    dst = wb + (size_t)w * CDIM * CDIM;
  }
  float4 v = ((const float4*)src)[i];
  ushort4 o;
  o.x = f2bf(v.x); o.y = f2bf(v.y); o.z = f2bf(v.z); o.w = f2bf(v.w);
  ((ushort4*)dst)[i] = o;
}

// ---------------------------------------------------------------------------
// QKV: A = xb [8192][1024], B = wb [3072][1024]. 1536 blocks = 8 XCD x 192.
// z==0/1 (K,Q): row-major writes. z==2 (V): transpose C-tile via LDS and
// write Vt[b][c][t] directly (replaces the separate transpose kernel and
// eliminates the V row-major round-trip).
__global__ void __launch_bounds__(256, 2) k_gemm_qkv_t(
    const u16* __restrict__ xb, const u16* __restrict__ wb,
    u16* __restrict__ kb, u16* __restrict__ qb, u16* __restrict__ vt)
{
  extern __shared__ char smem[];
  const int id = blockIdx.x;
  const int xcd = id & 7, loc = id >> 3;
  const int mt = xcd * 8 + (loc & 7);        // 0..63
  const int nt = loc >> 3;                   // 0..23
  const int m0 = mt * 128, n0g = nt * 128;

  f32x4 acc[4][4];
  ACC_ZERO4(acc);
  gemm128(xb, wb, CDIM, CDIM, m0, n0g, 16, smem, acc);

  const int tid = threadIdx.x, w = tid >> 6, l = tid & 63;
  const int wr = w >> 1, wc = w & 1;
  const int frow = l & 15, fko = l >> 4;
  const int z = n0g >> 10;
  if (z < 2) {
    u16* outp = (z == 0) ? kb : qb;
    const float scale = (z == 1) ? 0.03125f : 1.0f;
    const int r0 = m0 + wr * 64 + fko * 4;
    const int c0 = (n0g & 1023) + wc * 64 + frow;
#pragma unroll
    for (int mf = 0; mf < 4; ++mf)
#pragma unroll
      for (int nf = 0; nf < 4; ++nf) {
        const int r = r0 + mf * 16;
        const int c = c0 + nf * 16;
#pragma unroll
        for (int j = 0; j < 4; ++j)
          outp[(size_t)(r + j) * CDIM + c] = f2bf(acc[mf][nf][j] * scale);
      }
  } else {
    // V-transpose epilogue: tile[c][r], pitch 136 u16 (16B-aligned rows,
    // 2-way/free write banks). Then coalesced b128 writes to Vt.
    __syncthreads();
    u16* tile = (u16*)smem;  // [128][136]
#pragma unroll
    for (int mf = 0; mf < 4; ++mf)
#pragma unroll
      for (int nf = 0; nf < 4; ++nf) {
        const int cl = wc * 64 + nf * 16 + frow;
        const int rl = wr * 64 + mf * 16 + fko * 4;
#pragma unroll
        for (int j = 0; j < 4; ++j)
          tile[cl * 136 + rl + j] = f2bf(acc[mf][nf][j]);
      }
    __syncthreads();
    const int b = m0 >> 11, t0 = m0 & 2047;
    const int c0g = n0g - 2048;
    u16* dst = vt + ((size_t)b * CDIM + c0g) * TSEQ + t0;
#pragma unroll
    for (int it = 0; it < 8; ++it) {
      const int idx = it * 256 + tid;      // 0..2047
      const int c = idx >> 4, ch = idx & 15;
      bf16x8 v = *(const bf16x8*)(tile + c * 136 + ch * 8);
      *(bf16x8*)(dst + (size_t)c * TSEQ + ch * 8) = v;
    }
  }
}

// ---------------------------------------------------------------------------
// Scores: S = Q K^T -> P_unnorm = exp(S) bf16 (max-free) + rowsum partials.
// 544 blocks = 8 XCD x 68; per-batch 16x16 lower triangle of 128 tiles.
__global__ void __launch_bounds__(256, 2) k_gemm_scores_t(
    const u16* __restrict__ qb, const u16* __restrict__ kb,
    u16* __restrict__ pb, float* __restrict__ rs)
{
  extern __shared__ char smem[];
  const int id = blockIdx.x;
  const int sw = (id & 7) * 68 + (id >> 3);
  const int b = sw / 136;
  const int wq = sw - b * 136;
  int y = (int)((sqrtf(8.f * wq + 1.f) - 1.f) * 0.5f);
  while ((y + 1) * (y + 2) / 2 <= wq) ++y;
  while (y * (y + 1) / 2 > wq) --y;
  const int xt = wq - y * (y + 1) / 2;
  const int m0 = y * 128, n0 = xt * 128;

  const u16* A = qb + (size_t)b * TSEQ * CDIM;
  const u16* B = kb + (size_t)b * TSEQ * CDIM;
  u16* P = pb + (size_t)b * TSEQ * TSEQ;

  f32x4 acc[4][4];
  ACC_ZERO4(acc);
  gemm128(A, B, CDIM, CDIM, m0, n0, 16, smem, acc);

  const int tid = threadIdx.x, w = tid >> 6, l = tid & 63;
  const int wr = w >> 1, wc = w & 1;
  const int frow = l & 15, fko = l >> 4;
  float* rowpart = (float*)smem;

#pragma unroll
  for (int mf = 0; mf < 4; ++mf) {
#pragma unroll
    for (int j = 0; j < 4; ++j) {
      const int rloc = wr * 64 + mf * 16 + fko * 4 + j;
      const int rglob = m0 + rloc;
      float p4 = 0.f;
#pragma unroll
      for (int nf = 0; nf < 4; ++nf) {
        const int c = n0 + wc * 64 + nf * 16 + frow;
        float e = (c <= rglob) ? __expf(acc[mf][nf][j]) : 0.f;
        p4 += e;
        P[(size_t)rglob * TSEQ + c] = f2bf(e);
      }
#pragma unroll
      for (int d = 1; d < 16; d <<= 1) p4 += __shfl_xor(p4, d);
      if (frow == 0) rowpart[rloc * 2 + wc] = p4;
    }
  }
  __syncthreads();
  if (tid < 128)
    rs[((size_t)b * 16 + xt) * TSEQ + m0 + tid] =
        rowpart[tid * 2] + rowpart[tid * 2 + 1];
}

// ---------------------------------------------------------------------------
// O = (P_unnorm @ V) * inv_rowsum; causal K-extent nT = 2*(mt+1).
// inv computed inline from rs (suminv kernel fused away).
// 512 blocks = 8 XCD x 64; xcd = n (Vt panel resident), loc = b*16 + mt.
__global__ void __launch_bounds__(256, 2) k_gemm_pv_t(
    const u16* __restrict__ pb, const u16* __restrict__ vt,
    const float* __restrict__ rs, float* __restrict__ out)
{
  extern __shared__ char smem[];
  const int id = blockIdx.x;
  const int n = id & 7, loc = id >> 3;
  const int b = loc >> 4, mt = loc & 15;
  const int m0 = mt * 128, n0 = n * 128;
  const int nT = 2 * (mt + 1);

  const u16* A = pb + (size_t)b * TSEQ * TSEQ;
  const u16* B = vt + (size_t)b * CDIM * TSEQ;
  float* O = out + (size_t)b * TSEQ * CDIM;

  f32x4 acc[4][4];
  ACC_ZERO4(acc);
  gemm128(A, B, TSEQ, TSEQ, m0, n0, nT, smem, acc);

  const int tid = threadIdx.x, w = tid >> 6, l = tid & 63;
  const int wr = w >> 1, wc = w & 1;
  const int frow = l & 15, fko = l >> 4;

  // inline inv_rowsum for this block's 128 rows
  __syncthreads();
  float* sinv = (float*)smem;  // [128]
  if (tid < 128) {
    float s = 0.f;
    const float* p = rs + (size_t)b * 16 * TSEQ + m0 + tid;
    for (int x = 0; x <= mt; ++x) s += p[(size_t)x * TSEQ];
    sinv[tid] = 1.f / s;
  }
  __syncthreads();

#pragma unroll
  for (int mf = 0; mf < 4; ++mf) {
    const int rloc = wr * 64 + mf * 16 + fko * 4;
    const int r = m0 + rloc;
    const float4 iv = *(const float4*)&sinv[rloc];
    const float ivj[4] = {iv.x, iv.y, iv.z, iv.w};
#pragma unroll
    for (int nf = 0; nf < 4; ++nf) {
      const int c = n0 + wc * 64 + nf * 16 + frow;
#pragma unroll
      for (int j = 0; j < 4; ++j)
        O[(size_t)(r + j) * CDIM + c] = acc[mf][nf][j] * ivj[j];
    }
  }
}

// ---------------------------------------------------------------------------
extern "C" void kernel_launch(void* const* d_in, const int* in_sizes, int n_in,
                              void* d_out, int out_size, void* d_ws, size_t ws_size,
                              hipStream_t stream) {
  const float* x  = (const float*)d_in[0];
  const float* Wk = (const float*)d_in[1];
  const float* Wq = (const float*)d_in[2];
  const float* Wv = (const float*)d_in[3];
  float* out = (float*)d_out;

  const size_t M = (size_t)NBATCH * TSEQ;

  size_t off = 0;
  auto alloc = [&](size_t bytes) {
    void* p = (char*)d_ws + off;
    off += (bytes + 255) & ~(size_t)255;
    return p;
  };
  u16* xb = (u16*)alloc(M * CDIM * 2);                 // x bf16 (live all of qkv)
  u16* wb = (u16*)alloc(3ull * CDIM * CDIM * 2);       // Wk|Wq|Wv bf16
  u16* qb = (u16*)alloc(M * CDIM * 2);                 // Q (pre-scaled)
  u16* kb = (u16*)alloc(M * CDIM * 2);                 // K
  u16* vt = (u16*)alloc(M * CDIM * 2);                 // Vt [B][C][T] (dedicated)
  u16* pbuf = (u16*)alloc((size_t)NBATCH * TSEQ * TSEQ * 2);   // P_unnorm bf16
  float* rs = (float*)alloc((size_t)NBATCH * 16 * TSEQ * 4);   // rowsum partials
  if (off > ws_size) {
    fprintf(stderr, "kernel_launch: ws too small: need %zu, have %zu\n", off, ws_size);
    return;
  }

  const int NX4 = (NBATCH * TSEQ * CDIM) / 4;
  const int NW4 = (CDIM * CDIM) / 4;
  const int cvtBlocks = (NX4 + 3 * NW4) / 256;

  static_cast<void>(hipFuncSetAttribute(
      reinterpret_cast<const void*>(k_gemm_qkv_t),
      hipFuncAttributeMaxDynamicSharedMemorySize, 65536));
  static_cast<void>(hipFuncSetAttribute(
      reinterpret_cast<const void*>(k_gemm_scores_t),
      hipFuncAttributeMaxDynamicSharedMemorySize, 65536));
  static_cast<void>(hipFuncSetAttribute(
      reinterpret_cast<const void*>(k_gemm_pv_t),
      hipFuncAttributeMaxDynamicSharedMemorySize, 65536));

  k_cvt_all<<<cvtBlocks, 256, 0, stream>>>(x, Wk, Wq, Wv, xb, wb);
  k_gemm_qkv_t<<<1536, 256, 65536, stream>>>(xb, wb, kb, qb, vt);
  k_gemm_scores_t<<<544, 256, 65536, stream>>>(qb, kb, pbuf, rs);
  k_gemm_pv_t<<<512, 256, 65536, stream>>>(pbuf, vt, rs, out);
}

// Round 11
// 135.871 us; speedup vs baseline: 1.1215x; 1.0270x over previous
//
#include <hip/hip_runtime.h>
#include <cstdio>
#include <cmath>

#define TSEQ 2048
#define CDIM 1024
#define NBATCH 4

typedef float f32x4 __attribute__((ext_vector_type(4)));
typedef __bf16 bf16x8 __attribute__((ext_vector_type(8)));
typedef unsigned short u16;

// f32 -> bf16 round-to-nearest-even
__device__ __forceinline__ u16 f2bf(float f) {
  unsigned u = __builtin_bit_cast(unsigned, f);
  unsigned r = (u + 0x7FFFu + ((u >> 16) & 1u)) >> 16;
  return (u16)r;
}

// async global->LDS, 16B per lane; lds base wave-uniform (HW adds lane*16)
__device__ __forceinline__ void gload_lds16(const void* g, void* l) {
  __builtin_amdgcn_global_load_lds(
      (__attribute__((address_space(1))) void*)g,
      (__attribute__((address_space(3))) void*)l, 16, 0, 0);
}

// ---------------------------------------------------------------------------
// 4-wave 128x128 BK=64 core — RACE-FIXED schedule.
// Per K-tile t: vmcnt(8|0) -> barrier -> 16 ds_read_b128 -> 32 MFMA
// (setprio) -> barrier -> stage(t+2).
// stage(t+2) writes buf (t&1) ONLY after the post-MFMA barrier, i.e. after
// every wave's reads of tile t are consumed (data already in VGPRs). The old
// schedule issued stage(t+2) between the reads' ISSUE and their COMPLETION —
// a latent race amplified by LDS-pipe congestion (absmax drift R9/R10).
// Loads fly one full iteration (issued end of t, needed start of t+2).
// T2 3-bit XOR swizzle unchanged. nT even >= 2. LDS 64 KiB -> 2 blocks/CU.
// ---------------------------------------------------------------------------
#define SWZ2(b_) ((b_) ^ ((((b_) >> 7) & 7) << 4))

__device__ __forceinline__ void gemm128(
    const u16* __restrict__ A, const u16* __restrict__ B,
    int lda, int ldb, int m0, int n0, int nT,
    char* smem, f32x4 acc[4][4])
{
  u16* Ab = (u16*)smem;               // [2][128*64]
  u16* Bb = (u16*)(smem + 32768);     // [2][128*64]
  const int tid = threadIdx.x, w = tid >> 6, l = tid & 63;
  const int wr = w >> 1, wc = w & 1;
  const int frow = l & 15, fko = l >> 4;
  const int srow = l >> 3;
  const int scol = ((l & 7) * 8) ^ (((l >> 3) & 7) << 3);

  const u16* gA = A + (size_t)(m0 + w * 32 + srow) * lda + scol;
  const u16* gB = B + (size_t)(n0 + w * 32 + srow) * ldb + scol;

  auto stageA = [&](int t) {
    if (t >= nT) return;
    const u16* s = gA + t * 64;
    u16* d = Ab + (t & 1) * 8192 + w * 2048;
    gload_lds16(s, d);
    gload_lds16(s + (size_t)8 * lda, d + 512);
    gload_lds16(s + (size_t)16 * lda, d + 1024);
    gload_lds16(s + (size_t)24 * lda, d + 1536);
  };
  auto stageB = [&](int t) {
    if (t >= nT) return;
    const u16* s = gB + t * 64;
    u16* d = Bb + (t & 1) * 8192 + w * 2048;
    gload_lds16(s, d);
    gload_lds16(s + (size_t)8 * ldb, d + 512);
    gload_lds16(s + (size_t)16 * ldb, d + 1024);
    gload_lds16(s + (size_t)24 * ldb, d + 1536);
  };

#define AOFF(mf, ks) SWZ2(((wr * 64 + (mf) * 16 + frow) * 128 + (ks) * 64 + fko * 16))
#define BOFF(nf, ks) SWZ2(((wc * 64 + (nf) * 16 + frow) * 128 + (ks) * 64 + fko * 16))

  // prologue: tiles 0,1 staged (16 loads in flight)
  stageB(0); stageA(0); stageB(1); stageA(1);

#pragma unroll 1
  for (int t = 0; t < nT; ++t) {
    // tile t resident: all but the newest 8 (= stage(t+1)) must be done;
    // at t == nT-1 stage(nT) was a no-op, so drain fully.
    if (t < nT - 1) asm volatile("s_waitcnt vmcnt(8)" ::: "memory");
    else            asm volatile("s_waitcnt vmcnt(0)" ::: "memory");
    __builtin_amdgcn_s_barrier();
    __builtin_amdgcn_sched_barrier(0);   // pin reads after the barrier

    const char* Abase = (const char*)Ab + (t & 1) * 16384;
    const char* Bbase = (const char*)Bb + (t & 1) * 16384;
    bf16x8 bfr[4][2], afr[4][2];
#pragma unroll
    for (int nf = 0; nf < 4; ++nf)
#pragma unroll
      for (int ks = 0; ks < 2; ++ks)
        bfr[nf][ks] = *(const bf16x8*)(Bbase + BOFF(nf, ks));
#pragma unroll
    for (int mf = 0; mf < 4; ++mf)
#pragma unroll
      for (int ks = 0; ks < 2; ++ks)
        afr[mf][ks] = *(const bf16x8*)(Abase + AOFF(mf, ks));

    __builtin_amdgcn_s_setprio(1);
#pragma unroll
    for (int ks = 0; ks < 2; ++ks)
#pragma unroll
      for (int mf = 0; mf < 4; ++mf)
#pragma unroll
        for (int nf = 0; nf < 4; ++nf)
          acc[mf][nf] = __builtin_amdgcn_mfma_f32_16x16x32_bf16(
              afr[mf][ks], bfr[nf][ks], acc[mf][nf], 0, 0, 0);
    __builtin_amdgcn_s_setprio(0);

    __builtin_amdgcn_s_barrier();        // all waves consumed buf (t&1)
    __builtin_amdgcn_sched_barrier(0);   // pin stages after the barrier
    stageB(t + 2);                       // buf (t&1) now dead -> safe
    stageA(t + 2);
  }
#undef AOFF
#undef BOFF
}

#define ACC_ZERO4(acc)                                  \
  _Pragma("unroll") for (int m_ = 0; m_ < 4; ++m_)      \
  _Pragma("unroll") for (int n_ = 0; n_ < 4; ++n_)      \
      acc[m_][n_] = (f32x4){0.f, 0.f, 0.f, 0.f};

// ---------------------------------------------------------------------------
// single cvt kernel for x, Wk, Wq, Wv
__global__ void __launch_bounds__(256) k_cvt_all(
    const float* __restrict__ x, const float* __restrict__ Wk,
    const float* __restrict__ Wq, const float* __restrict__ Wv,
    u16* __restrict__ xb, u16* __restrict__ wb)
{
  const int NX4 = (NBATCH * TSEQ * CDIM) / 4;
  const int NW4 = (CDIM * CDIM) / 4;
  int g = blockIdx.x * 256 + threadIdx.x;
  const float* src; u16* dst; int i;
  if (g < NX4) { src = x; dst = xb; i = g; }
  else {
    int g2 = g - NX4;
    int w = g2 / NW4; i = g2 - w * NW4;
    src = (w == 0) ? Wk : (w == 1) ? Wq : Wv;
    dst = wb + (size_t)w * CDIM * CDIM;
  }
  float4 v = ((const float4*)src)[i];
  ushort4 o;
  o.x = f2bf(v.x); o.y = f2bf(v.y); o.z = f2bf(v.z); o.w = f2bf(v.w);
  ((ushort4*)dst)[i] = o;
}

// ---------------------------------------------------------------------------
// QKV: A = xb [8192][1024], B = wb [3072][1024]. 1536 blocks = 8 XCD x 192.
// z==0/1 (K,Q): LDS-repacked coalesced row-major writes (bf16x8).
// z==2 (V): transpose C-tile via LDS, write Vt[b][c][t] directly.
__global__ void __launch_bounds__(256, 2) k_gemm_qkv_t(
    const u16* __restrict__ xb, const u16* __restrict__ wb,
    u16* __restrict__ kb, u16* __restrict__ qb, u16* __restrict__ vt)
{
  extern __shared__ char smem[];
  const int id = blockIdx.x;
  const int xcd = id & 7, loc = id >> 3;
  const int mt = xcd * 8 + (loc & 7);        // 0..63
  const int nt = loc >> 3;                   // 0..23
  const int m0 = mt * 128, n0g = nt * 128;

  f32x4 acc[4][4];
  ACC_ZERO4(acc);
  gemm128(xb, wb, CDIM, CDIM, m0, n0g, 16, smem, acc);

  const int tid = threadIdx.x, w = tid >> 6, l = tid & 63;
  const int wr = w >> 1, wc = w & 1;
  const int frow = l & 15, fko = l >> 4;
  const int z = n0g >> 10;
  u16* tile = (u16*)smem;  // [128][136] u16 (16B-aligned rows)
  __syncthreads();          // fence: gemm LDS fully dead on all waves
  if (z < 2) {
    u16* outp = (z == 0) ? kb : qb;
    const float scale = (z == 1) ? 0.03125f : 1.0f;
#pragma unroll
    for (int mf = 0; mf < 4; ++mf)
#pragma unroll
      for (int nf = 0; nf < 4; ++nf) {
        const int rl = wr * 64 + mf * 16 + fko * 4;
        const int cl = wc * 64 + nf * 16 + frow;
#pragma unroll
        for (int j = 0; j < 4; ++j)
          tile[(rl + j) * 136 + cl] = f2bf(acc[mf][nf][j] * scale);
      }
    __syncthreads();
    u16* dst = outp + (size_t)m0 * CDIM + (n0g & 1023);
#pragma unroll
    for (int it = 0; it < 8; ++it) {
      const int idx = it * 256 + tid;      // 0..2047
      const int r = idx >> 4, ch = idx & 15;
      *(bf16x8*)(dst + (size_t)r * CDIM + ch * 8) =
          *(const bf16x8*)(tile + r * 136 + ch * 8);
    }
  } else {
    // V-transpose epilogue: tile[c][r]; coalesced b128 writes to Vt.
#pragma unroll
    for (int mf = 0; mf < 4; ++mf)
#pragma unroll
      for (int nf = 0; nf < 4; ++nf) {
        const int cl = wc * 64 + nf * 16 + frow;
        const int rl = wr * 64 + mf * 16 + fko * 4;
#pragma unroll
        for (int j = 0; j < 4; ++j)
          tile[cl * 136 + rl + j] = f2bf(acc[mf][nf][j]);
      }
    __syncthreads();
    const int b = m0 >> 11, t0 = m0 & 2047;
    const int c0g = n0g - 2048;
    u16* dst = vt + ((size_t)b * CDIM + c0g) * TSEQ + t0;
#pragma unroll
    for (int it = 0; it < 8; ++it) {
      const int idx = it * 256 + tid;      // 0..2047
      const int c = idx >> 4, ch = idx & 15;
      *(bf16x8*)(dst + (size_t)c * TSEQ + ch * 8) =
          *(const bf16x8*)(tile + c * 136 + ch * 8);
    }
  }
}

// ---------------------------------------------------------------------------
// Scores: S = Q K^T -> P_unnorm = exp(S) bf16 (max-free) + rowsum partials.
// 544 blocks = 8 XCD x 68; per-batch 16x16 lower triangle of 128 tiles.
// Epilogue: exp+rowsum fused with LDS repack -> coalesced bf16x8 P writes.
__global__ void __launch_bounds__(256, 2) k_gemm_scores_t(
    const u16* __restrict__ qb, const u16* __restrict__ kb,
    u16* __restrict__ pb, float* __restrict__ rs)
{
  extern __shared__ char smem[];
  const int id = blockIdx.x;
  const int sw = (id & 7) * 68 + (id >> 3);
  const int b = sw / 136;
  const int wq = sw - b * 136;
  int y = (int)((sqrtf(8.f * wq + 1.f) - 1.f) * 0.5f);
  while ((y + 1) * (y + 2) / 2 <= wq) ++y;
  while (y * (y + 1) / 2 > wq) --y;
  const int xt = wq - y * (y + 1) / 2;
  const int m0 = y * 128, n0 = xt * 128;

  const u16* A = qb + (size_t)b * TSEQ * CDIM;
  const u16* B = kb + (size_t)b * TSEQ * CDIM;
  u16* P = pb + (size_t)b * TSEQ * TSEQ;

  f32x4 acc[4][4];
  ACC_ZERO4(acc);
  gemm128(A, B, CDIM, CDIM, m0, n0, 16, smem, acc);

  const int tid = threadIdx.x, w = tid >> 6, l = tid & 63;
  const int wr = w >> 1, wc = w & 1;
  const int frow = l & 15, fko = l >> 4;
  u16* tile = (u16*)smem;                     // [128][136] u16
  float* rowpart = (float*)(smem + 34816);    // [128][2] f32

  __syncthreads();  // fence: gemm LDS fully dead on all waves
#pragma unroll
  for (int mf = 0; mf < 4; ++mf) {
#pragma unroll
    for (int j = 0; j < 4; ++j) {
      const int rloc = wr * 64 + mf * 16 + fko * 4 + j;
      const int rglob = m0 + rloc;
      float p4 = 0.f;
#pragma unroll
      for (int nf = 0; nf < 4; ++nf) {
        const int cl = wc * 64 + nf * 16 + frow;
        const int c = n0 + cl;
        float e = (c <= rglob) ? __expf(acc[mf][nf][j]) : 0.f;
        p4 += e;
        tile[rloc * 136 + cl] = f2bf(e);
      }
#pragma unroll
      for (int d = 1; d < 16; d <<= 1) p4 += __shfl_xor(p4, d);
      if (frow == 0) rowpart[rloc * 2 + wc] = p4;
    }
  }
  __syncthreads();
  u16* dst = P + (size_t)m0 * TSEQ + n0;
#pragma unroll
  for (int it = 0; it < 8; ++it) {
    const int idx = it * 256 + tid;          // 0..2047
    const int r = idx >> 4, ch = idx & 15;
    *(bf16x8*)(dst + (size_t)r * TSEQ + ch * 8) =
        *(const bf16x8*)(tile + r * 136 + ch * 8);
  }
  if (tid < 128)
    rs[((size_t)b * 16 + xt) * TSEQ + m0 + tid] =
        rowpart[tid * 2] + rowpart[tid * 2 + 1];
}

// ---------------------------------------------------------------------------
// O = (P_unnorm @ V) * inv_rowsum; causal K-extent nT = 2*(mt+1).
// inv computed inline from rs. 512 blocks = 8 XCD x 64.
__global__ void __launch_bounds__(256, 2) k_gemm_pv_t(
    const u16* __restrict__ pb, const u16* __restrict__ vt,
    const float* __restrict__ rs, float* __restrict__ out)
{
  extern __shared__ char smem[];
  const int id = blockIdx.x;
  const int n = id & 7, loc = id >> 3;
  const int b = loc >> 4, mt = loc & 15;
  const int m0 = mt * 128, n0 = n * 128;
  const int nT = 2 * (mt + 1);

  const u16* A = pb + (size_t)b * TSEQ * TSEQ;
  const u16* B = vt + (size_t)b * CDIM * TSEQ;
  float* O = out + (size_t)b * TSEQ * CDIM;

  f32x4 acc[4][4];
  ACC_ZERO4(acc);
  gemm128(A, B, TSEQ, TSEQ, m0, n0, nT, smem, acc);

  const int tid = threadIdx.x, w = tid >> 6, l = tid & 63;
  const int wr = w >> 1, wc = w & 1;
  const int frow = l & 15, fko = l >> 4;

  // inline inv_rowsum for this block's 128 rows
  __syncthreads();
  float* sinv = (float*)smem;  // [128]
  if (tid < 128) {
    float s = 0.f;
    const float* p = rs + (size_t)b * 16 * TSEQ + m0 + tid;
    for (int x = 0; x <= mt; ++x) s += p[(size_t)x * TSEQ];
    sinv[tid] = 1.f / s;
  }
  __syncthreads();

#pragma unroll
  for (int mf = 0; mf < 4; ++mf) {
    const int rloc = wr * 64 + mf * 16 + fko * 4;
    const int r = m0 + rloc;
    const float4 iv = *(const float4*)&sinv[rloc];
    const float ivj[4] = {iv.x, iv.y, iv.z, iv.w};
#pragma unroll
    for (int nf = 0; nf < 4; ++nf) {
      const int c = n0 + wc * 64 + nf * 16 + frow;
#pragma unroll
      for (int j = 0; j < 4; ++j)
        O[(size_t)(r + j) * CDIM + c] = acc[mf][nf][j] * ivj[j];
    }
  }
}

// ---------------------------------------------------------------------------
extern "C" void kernel_launch(void* const* d_in, const int* in_sizes, int n_in,
                              void* d_out, int out_size, void* d_ws, size_t ws_size,
                              hipStream_t stream) {
  const float* x  = (const float*)d_in[0];
  const float* Wk = (const float*)d_in[1];
  const float* Wq = (const float*)d_in[2];
  const float* Wv = (const float*)d_in[3];
  float* out = (float*)d_out;

  const size_t M = (size_t)NBATCH * TSEQ;

  size_t off = 0;
  auto alloc = [&](size_t bytes) {
    void* p = (char*)d_ws + off;
    off += (bytes + 255) & ~(size_t)255;
    return p;
  };
  u16* xb = (u16*)alloc(M * CDIM * 2);                 // x bf16 (live all of qkv)
  u16* wb = (u16*)alloc(3ull * CDIM * CDIM * 2);       // Wk|Wq|Wv bf16
  u16* qb = (u16*)alloc(M * CDIM * 2);                 // Q (pre-scaled)
  u16* kb = (u16*)alloc(M * CDIM * 2);                 // K
  u16* vt = (u16*)alloc(M * CDIM * 2);                 // Vt [B][C][T]
  u16* pbuf = (u16*)alloc((size_t)NBATCH * TSEQ * TSEQ * 2);   // P_unnorm bf16
  float* rs = (float*)alloc((size_t)NBATCH * 16 * TSEQ * 4);   // rowsum partials
  if (off > ws_size) {
    fprintf(stderr, "kernel_launch: ws too small: need %zu, have %zu\n", off, ws_size);
    return;
  }

  const int NX4 = (NBATCH * TSEQ * CDIM) / 4;
  const int NW4 = (CDIM * CDIM) / 4;
  const int cvtBlocks = (NX4 + 3 * NW4) / 256;

  static_cast<void>(hipFuncSetAttribute(
      reinterpret_cast<const void*>(k_gemm_qkv_t),
      hipFuncAttributeMaxDynamicSharedMemorySize, 65536));
  static_cast<void>(hipFuncSetAttribute(
      reinterpret_cast<const void*>(k_gemm_scores_t),
      hipFuncAttributeMaxDynamicSharedMemorySize, 65536));
  static_cast<void>(hipFuncSetAttribute(
      reinterpret_cast<const void*>(k_gemm_pv_t),
      hipFuncAttributeMaxDynamicSharedMemorySize, 65536));

  k_cvt_all<<<cvtBlocks, 256, 0, stream>>>(x, Wk, Wq, Wv, xb, wb);
  k_gemm_qkv_t<<<1536, 256, 65536, stream>>>(xb, wb, kb, qb, vt);
  k_gemm_scores_t<<<544, 256, 65536, stream>>>(qb, kb, pbuf, rs);
  k_gemm_pv_t<<<512, 256, 65536, stream>>>(pbuf, vt, rs, out);
}

// Round 12
// 130.109 us; speedup vs baseline: 1.1712x; 1.0443x over previous
//
#include <hip/hip_runtime.h>
#include <cstdio>
#include <cmath>

#define TSEQ 2048
#define CDIM 1024
#define NBATCH 4

typedef float f32x4 __attribute__((ext_vector_type(4)));
typedef __bf16 bf16x8 __attribute__((ext_vector_type(8)));
typedef unsigned short u16;
typedef u16 u16x8 __attribute__((ext_vector_type(8)));

// f32 -> bf16 round-to-nearest-even
__device__ __forceinline__ u16 f2bf(float f) {
  unsigned u = __builtin_bit_cast(unsigned, f);
  unsigned r = (u + 0x7FFFu + ((u >> 16) & 1u)) >> 16;
  return (u16)r;
}

// async global->LDS, 16B per lane; lds base wave-uniform (HW adds lane*16)
__device__ __forceinline__ void gload_lds16(const void* g, void* l) {
  __builtin_amdgcn_global_load_lds(
      (__attribute__((address_space(1))) void*)g,
      (__attribute__((address_space(3))) void*)l, 16, 0, 0);
}

// ---------------------------------------------------------------------------
// 4-wave 128x128 BK=64 core — race-fixed schedule (R11, verified).
// Per K-tile t: vmcnt(8|0) -> barrier -> 16 ds_read_b128 -> 32 MFMA
// (setprio) -> barrier -> stage(t+2). T2 3-bit XOR swizzle.
// nT even >= 2. LDS 64 KiB -> 2 blocks/CU.
// ---------------------------------------------------------------------------
#define SWZ2(b_) ((b_) ^ ((((b_) >> 7) & 7) << 4))

__device__ __forceinline__ void gemm128(
    const u16* __restrict__ A, const u16* __restrict__ B,
    int lda, int ldb, int m0, int n0, int nT,
    char* smem, f32x4 acc[4][4])
{
  u16* Ab = (u16*)smem;               // [2][128*64]
  u16* Bb = (u16*)(smem + 32768);     // [2][128*64]
  const int tid = threadIdx.x, w = tid >> 6, l = tid & 63;
  const int wr = w >> 1, wc = w & 1;
  const int frow = l & 15, fko = l >> 4;
  const int srow = l >> 3;
  const int scol = ((l & 7) * 8) ^ (((l >> 3) & 7) << 3);

  const u16* gA = A + (size_t)(m0 + w * 32 + srow) * lda + scol;
  const u16* gB = B + (size_t)(n0 + w * 32 + srow) * ldb + scol;

  auto stageA = [&](int t) {
    if (t >= nT) return;
    const u16* s = gA + t * 64;
    u16* d = Ab + (t & 1) * 8192 + w * 2048;
    gload_lds16(s, d);
    gload_lds16(s + (size_t)8 * lda, d + 512);
    gload_lds16(s + (size_t)16 * lda, d + 1024);
    gload_lds16(s + (size_t)24 * lda, d + 1536);
  };
  auto stageB = [&](int t) {
    if (t >= nT) return;
    const u16* s = gB + t * 64;
    u16* d = Bb + (t & 1) * 8192 + w * 2048;
    gload_lds16(s, d);
    gload_lds16(s + (size_t)8 * ldb, d + 512);
    gload_lds16(s + (size_t)16 * ldb, d + 1024);
    gload_lds16(s + (size_t)24 * ldb, d + 1536);
  };

#define AOFF(mf, ks) SWZ2(((wr * 64 + (mf) * 16 + frow) * 128 + (ks) * 64 + fko * 16))
#define BOFF(nf, ks) SWZ2(((wc * 64 + (nf) * 16 + frow) * 128 + (ks) * 64 + fko * 16))

  // prologue: tiles 0,1 staged (16 loads in flight)
  stageB(0); stageA(0); stageB(1); stageA(1);

#pragma unroll 1
  for (int t = 0; t < nT; ++t) {
    if (t < nT - 1) asm volatile("s_waitcnt vmcnt(8)" ::: "memory");
    else            asm volatile("s_waitcnt vmcnt(0)" ::: "memory");
    __builtin_amdgcn_s_barrier();
    __builtin_amdgcn_sched_barrier(0);   // pin reads after the barrier

    const char* Abase = (const char*)Ab + (t & 1) * 16384;
    const char* Bbase = (const char*)Bb + (t & 1) * 16384;
    bf16x8 bfr[4][2], afr[4][2];
#pragma unroll
    for (int nf = 0; nf < 4; ++nf)
#pragma unroll
      for (int ks = 0; ks < 2; ++ks)
        bfr[nf][ks] = *(const bf16x8*)(Bbase + BOFF(nf, ks));
#pragma unroll
    for (int mf = 0; mf < 4; ++mf)
#pragma unroll
      for (int ks = 0; ks < 2; ++ks)
        afr[mf][ks] = *(const bf16x8*)(Abase + AOFF(mf, ks));

    __builtin_amdgcn_s_setprio(1);
#pragma unroll
    for (int ks = 0; ks < 2; ++ks)
#pragma unroll
      for (int mf = 0; mf < 4; ++mf)
#pragma unroll
        for (int nf = 0; nf < 4; ++nf)
          acc[mf][nf] = __builtin_amdgcn_mfma_f32_16x16x32_bf16(
              afr[mf][ks], bfr[nf][ks], acc[mf][nf], 0, 0, 0);
    __builtin_amdgcn_s_setprio(0);

    __builtin_amdgcn_s_barrier();        // all waves consumed buf (t&1)
    __builtin_amdgcn_sched_barrier(0);   // pin stages after the barrier
    stageB(t + 2);                       // buf (t&1) now dead -> safe
    stageA(t + 2);
  }
#undef AOFF
#undef BOFF
}

#define ACC_ZERO4(acc)                                  \
  _Pragma("unroll") for (int m_ = 0; m_ < 4; ++m_)      \
  _Pragma("unroll") for (int n_ = 0; n_ < 4; ++n_)      \
      acc[m_][n_] = (f32x4){0.f, 0.f, 0.f, 0.f};

// ---------------------------------------------------------------------------
// cvt: 8 elems/thread, bf16x8 16B stores
__global__ void __launch_bounds__(256) k_cvt_all(
    const float* __restrict__ x, const float* __restrict__ Wk,
    const float* __restrict__ Wq, const float* __restrict__ Wv,
    u16* __restrict__ xb, u16* __restrict__ wb)
{
  const int NX8 = (NBATCH * TSEQ * CDIM) / 8;   // 1,048,576
  const int NW8 = (CDIM * CDIM) / 8;            // 131,072
  int g = blockIdx.x * 256 + threadIdx.x;
  const float* src; u16* dst; int i;
  if (g < NX8) { src = x; dst = xb; i = g; }
  else {
    int g2 = g - NX8;
    int w = g2 / NW8; i = g2 - w * NW8;
    src = (w == 0) ? Wk : (w == 1) ? Wq : Wv;
    dst = wb + (size_t)w * CDIM * CDIM;
  }
  float4 v0 = ((const float4*)src)[2 * i];
  float4 v1 = ((const float4*)src)[2 * i + 1];
  u16x8 o;
  o[0] = f2bf(v0.x); o[1] = f2bf(v0.y); o[2] = f2bf(v0.z); o[3] = f2bf(v0.w);
  o[4] = f2bf(v1.x); o[5] = f2bf(v1.y); o[6] = f2bf(v1.z); o[7] = f2bf(v1.w);
  *(u16x8*)(dst + (size_t)8 * i) = o;
}

// ---------------------------------------------------------------------------
// QKV: A = xb [8192][1024], B = wb [3072][1024]. 1536 blocks = 8 XCD x 192.
// z==0/1 (K,Q): LDS-repacked coalesced row-major writes (bf16x8).
// z==2 (V): transpose C-tile via LDS, write Vt[b][c][t] directly.
__global__ void __launch_bounds__(256, 2) k_gemm_qkv_t(
    const u16* __restrict__ xb, const u16* __restrict__ wb,
    u16* __restrict__ kb, u16* __restrict__ qb, u16* __restrict__ vt)
{
  extern __shared__ char smem[];
  const int id = blockIdx.x;
  const int xcd = id & 7, loc = id >> 3;
  const int mt = xcd * 8 + (loc & 7);        // 0..63
  const int nt = loc >> 3;                   // 0..23
  const int m0 = mt * 128, n0g = nt * 128;

  f32x4 acc[4][4];
  ACC_ZERO4(acc);
  gemm128(xb, wb, CDIM, CDIM, m0, n0g, 16, smem, acc);

  const int tid = threadIdx.x, w = tid >> 6, l = tid & 63;
  const int wr = w >> 1, wc = w & 1;
  const int frow = l & 15, fko = l >> 4;
  const int z = n0g >> 10;
  u16* tile = (u16*)smem;  // [128][136] u16 (16B-aligned rows)
  __syncthreads();          // fence: gemm LDS fully dead on all waves
  if (z < 2) {
    u16* outp = (z == 0) ? kb : qb;
    const float scale = (z == 1) ? 0.03125f : 1.0f;
#pragma unroll
    for (int mf = 0; mf < 4; ++mf)
#pragma unroll
      for (int nf = 0; nf < 4; ++nf) {
        const int rl = wr * 64 + mf * 16 + fko * 4;
        const int cl = wc * 64 + nf * 16 + frow;
#pragma unroll
        for (int j = 0; j < 4; ++j)
          tile[(rl + j) * 136 + cl] = f2bf(acc[mf][nf][j] * scale);
      }
    __syncthreads();
    u16* dst = outp + (size_t)m0 * CDIM + (n0g & 1023);
#pragma unroll
    for (int it = 0; it < 8; ++it) {
      const int idx = it * 256 + tid;      // 0..2047
      const int r = idx >> 4, ch = idx & 15;
      *(bf16x8*)(dst + (size_t)r * CDIM + ch * 8) =
          *(const bf16x8*)(tile + r * 136 + ch * 8);
    }
  } else {
    // V-transpose epilogue: tile[c][r]; coalesced b128 writes to Vt.
#pragma unroll
    for (int mf = 0; mf < 4; ++mf)
#pragma unroll
      for (int nf = 0; nf < 4; ++nf) {
        const int cl = wc * 64 + nf * 16 + frow;
        const int rl = wr * 64 + mf * 16 + fko * 4;
#pragma unroll
        for (int j = 0; j < 4; ++j)
          tile[cl * 136 + rl + j] = f2bf(acc[mf][nf][j]);
      }
    __syncthreads();
    const int b = m0 >> 11, t0 = m0 & 2047;
    const int c0g = n0g - 2048;
    u16* dst = vt + ((size_t)b * CDIM + c0g) * TSEQ + t0;
#pragma unroll
    for (int it = 0; it < 8; ++it) {
      const int idx = it * 256 + tid;      // 0..2047
      const int c = idx >> 4, ch = idx & 15;
      *(bf16x8*)(dst + (size_t)c * TSEQ + ch * 8) =
          *(const bf16x8*)(tile + c * 136 + ch * 8);
    }
  }
}

// ---------------------------------------------------------------------------
// Scores: S = Q K^T -> P_unnorm = exp(S) bf16 (max-free) + rowsum partials.
// 544 blocks = 8 XCD x 68; per-batch 16x16 lower triangle of 128 tiles.
__global__ void __launch_bounds__(256, 2) k_gemm_scores_t(
    const u16* __restrict__ qb, const u16* __restrict__ kb,
    u16* __restrict__ pb, float* __restrict__ rs)
{
  extern __shared__ char smem[];
  const int id = blockIdx.x;
  const int sw = (id & 7) * 68 + (id >> 3);
  const int b = sw / 136;
  const int wq = sw - b * 136;
  int y = (int)((sqrtf(8.f * wq + 1.f) - 1.f) * 0.5f);
  while ((y + 1) * (y + 2) / 2 <= wq) ++y;
  while (y * (y + 1) / 2 > wq) --y;
  const int xt = wq - y * (y + 1) / 2;
  const int m0 = y * 128, n0 = xt * 128;

  const u16* A = qb + (size_t)b * TSEQ * CDIM;
  const u16* B = kb + (size_t)b * TSEQ * CDIM;
  u16* P = pb + (size_t)b * TSEQ * TSEQ;

  f32x4 acc[4][4];
  ACC_ZERO4(acc);
  gemm128(A, B, CDIM, CDIM, m0, n0, 16, smem, acc);

  const int tid = threadIdx.x, w = tid >> 6, l = tid & 63;
  const int wr = w >> 1, wc = w & 1;
  const int frow = l & 15, fko = l >> 4;
  u16* tile = (u16*)smem;                     // [128][136] u16
  float* rowpart = (float*)(smem + 34816);    // [128][2] f32

  __syncthreads();  // fence: gemm LDS fully dead on all waves
#pragma unroll
  for (int mf = 0; mf < 4; ++mf) {
#pragma unroll
    for (int j = 0; j < 4; ++j) {
      const int rloc = wr * 64 + mf * 16 + fko * 4 + j;
      const int rglob = m0 + rloc;
      float p4 = 0.f;
#pragma unroll
      for (int nf = 0; nf < 4; ++nf) {
        const int cl = wc * 64 + nf * 16 + frow;
        const int c = n0 + cl;
        float e = (c <= rglob) ? __expf(acc[mf][nf][j]) : 0.f;
        p4 += e;
        tile[rloc * 136 + cl] = f2bf(e);
      }
#pragma unroll
      for (int d = 1; d < 16; d <<= 1) p4 += __shfl_xor(p4, d);
      if (frow == 0) rowpart[rloc * 2 + wc] = p4;
    }
  }
  __syncthreads();
  u16* dst = P + (size_t)m0 * TSEQ + n0;
#pragma unroll
  for (int it = 0; it < 8; ++it) {
    const int idx = it * 256 + tid;          // 0..2047
    const int r = idx >> 4, ch = idx & 15;
    *(bf16x8*)(dst + (size_t)r * TSEQ + ch * 8) =
        *(const bf16x8*)(tile + r * 136 + ch * 8);
  }
  if (tid < 128)
    rs[((size_t)b * 16 + xt) * TSEQ + m0 + tid] =
        rowpart[tid * 2] + rowpart[tid * 2 + 1];
}

// ---------------------------------------------------------------------------
// O = (P_unnorm @ V) * inv_rowsum; causal K-extent nT = 2*(mt+1).
// inv computed inline from rs. 512 blocks = 8 XCD x 64.
// Load-balance: loc and loc+32 (same CU under round-robin) carry
// complementary mt (sum 15) -> every CU gets exactly 34 K-tiles.
__global__ void __launch_bounds__(256, 2) k_gemm_pv_t(
    const u16* __restrict__ pb, const u16* __restrict__ vt,
    const float* __restrict__ rs, float* __restrict__ out)
{
  extern __shared__ char smem[];
  const int id = blockIdx.x;
  const int n = id & 7, loc = id >> 3;   // loc 0..63
  int b, mt;
  if (loc < 32) { mt = 15 - (loc & 15); b = loc >> 4; }
  else          { mt = loc & 15;        b = 2 + ((loc - 32) >> 4); }
  const int m0 = mt * 128, n0 = n * 128;
  const int nT = 2 * (mt + 1);

  const u16* A = pb + (size_t)b * TSEQ * TSEQ;
  const u16* B = vt + (size_t)b * CDIM * TSEQ;
  float* O = out + (size_t)b * TSEQ * CDIM;

  f32x4 acc[4][4];
  ACC_ZERO4(acc);
  gemm128(A, B, TSEQ, TSEQ, m0, n0, nT, smem, acc);

  const int tid = threadIdx.x, w = tid >> 6, l = tid & 63;
  const int wr = w >> 1, wc = w & 1;
  const int frow = l & 15, fko = l >> 4;

  // inline inv_rowsum for this block's 128 rows
  __syncthreads();
  float* sinv = (float*)smem;  // [128]
  if (tid < 128) {
    float s = 0.f;
    const float* p = rs + (size_t)b * 16 * TSEQ + m0 + tid;
    for (int x = 0; x <= mt; ++x) s += p[(size_t)x * TSEQ];
    sinv[tid] = 1.f / s;
  }
  __syncthreads();

#pragma unroll
  for (int mf = 0; mf < 4; ++mf) {
    const int rloc = wr * 64 + mf * 16 + fko * 4;
    const int r = m0 + rloc;
    const float4 iv = *(const float4*)&sinv[rloc];
    const float ivj[4] = {iv.x, iv.y, iv.z, iv.w};
#pragma unroll
    for (int nf = 0; nf < 4; ++nf) {
      const int c = n0 + wc * 64 + nf * 16 + frow;
#pragma unroll
      for (int j = 0; j < 4; ++j)
        O[(size_t)(r + j) * CDIM + c] = acc[mf][nf][j] * ivj[j];
    }
  }
}

// ---------------------------------------------------------------------------
extern "C" void kernel_launch(void* const* d_in, const int* in_sizes, int n_in,
                              void* d_out, int out_size, void* d_ws, size_t ws_size,
                              hipStream_t stream) {
  const float* x  = (const float*)d_in[0];
  const float* Wk = (const float*)d_in[1];
  const float* Wq = (const float*)d_in[2];
  const float* Wv = (const float*)d_in[3];
  float* out = (float*)d_out;

  const size_t M = (size_t)NBATCH * TSEQ;

  size_t off = 0;
  auto alloc = [&](size_t bytes) {
    void* p = (char*)d_ws + off;
    off += (bytes + 255) & ~(size_t)255;
    return p;
  };
  u16* xb = (u16*)alloc(M * CDIM * 2);                 // x bf16 (live all of qkv)
  u16* wb = (u16*)alloc(3ull * CDIM * CDIM * 2);       // Wk|Wq|Wv bf16
  u16* qb = (u16*)alloc(M * CDIM * 2);                 // Q (pre-scaled)
  u16* kb = (u16*)alloc(M * CDIM * 2);                 // K
  u16* vt = (u16*)alloc(M * CDIM * 2);                 // Vt [B][C][T]
  u16* pbuf = (u16*)alloc((size_t)NBATCH * TSEQ * TSEQ * 2);   // P_unnorm bf16
  float* rs = (float*)alloc((size_t)NBATCH * 16 * TSEQ * 4);   // rowsum partials
  if (off > ws_size) {
    fprintf(stderr, "kernel_launch: ws too small: need %zu, have %zu\n", off, ws_size);
    return;
  }

  const int NX8 = (NBATCH * TSEQ * CDIM) / 8;
  const int NW8 = (CDIM * CDIM) / 8;
  const int cvtBlocks = (NX8 + 3 * NW8) / 256;

  static_cast<void>(hipFuncSetAttribute(
      reinterpret_cast<const void*>(k_gemm_qkv_t),
      hipFuncAttributeMaxDynamicSharedMemorySize, 65536));
  static_cast<void>(hipFuncSetAttribute(
      reinterpret_cast<const void*>(k_gemm_scores_t),
      hipFuncAttributeMaxDynamicSharedMemorySize, 65536));
  static_cast<void>(hipFuncSetAttribute(
      reinterpret_cast<const void*>(k_gemm_pv_t),
      hipFuncAttributeMaxDynamicSharedMemorySize, 65536));

  k_cvt_all<<<cvtBlocks, 256, 0, stream>>>(x, Wk, Wq, Wv, xb, wb);
  k_gemm_qkv_t<<<1536, 256, 65536, stream>>>(xb, wb, kb, qb, vt);
  k_gemm_scores_t<<<544, 256, 65536, stream>>>(qb, kb, pbuf, rs);
  k_gemm_pv_t<<<512, 256, 65536, stream>>>(pbuf, vt, rs, out);
}

// Round 13
// 128.333 us; speedup vs baseline: 1.1874x; 1.0138x over previous
//
#include <hip/hip_runtime.h>
#include <cstdio>
#include <cmath>

#define TSEQ 2048
#define CDIM 1024
#define NBATCH 4

typedef float f32x4 __attribute__((ext_vector_type(4)));
typedef __bf16 bf16x8 __attribute__((ext_vector_type(8)));
typedef unsigned short u16;
typedef u16 u16x8 __attribute__((ext_vector_type(8)));

// f32 -> bf16 round-to-nearest-even
__device__ __forceinline__ u16 f2bf(float f) {
  unsigned u = __builtin_bit_cast(unsigned, f);
  unsigned r = (u + 0x7FFFu + ((u >> 16) & 1u)) >> 16;
  return (u16)r;
}

// async global->LDS, 16B per lane; lds base wave-uniform (HW adds lane*16)
__device__ __forceinline__ void gload_lds16(const void* g, void* l) {
  __builtin_amdgcn_global_load_lds(
      (__attribute__((address_space(1))) void*)g,
      (__attribute__((address_space(3))) void*)l, 16, 0, 0);
}

// ---------------------------------------------------------------------------
// 4-wave 128x128 BK=64 core — R13: reads(t+1) OVERLAP MFMA(t) via register
// double-buffered fragments (sets s0/s1, static indexing).
// Window t: vmcnt(8|0) -> barrier -> [RD(t+1) || MFMA(t)] -> lgkmcnt(0)
//           -> barrier -> stage(t+3).
// Invariants (race-free, R11 lineage):
//  - stage(x) writes buf[x&1] only after lgkmcnt(0)+barrier proves all
//    waves' reads of tile x-2 (same buffer) completed (frags live in regs).
//  - RD(t+1) requires stage(t+1) landed: head vmcnt(8) leaves only
//    stage(t+2) (8 newest) in flight -> stage(t+1), issued 2 windows ago,
//    is complete. At t >= nT-2 no newer stage exists -> vmcnt(0).
// T2 3-bit XOR swizzle. nT even >= 2. LDS 64 KiB -> 2 blocks/CU (TLP).
// ---------------------------------------------------------------------------
#define SWZ2(b_) ((b_) ^ ((((b_) >> 7) & 7) << 4))

__device__ __forceinline__ void gemm128(
    const u16* __restrict__ A, const u16* __restrict__ B,
    int lda, int ldb, int m0, int n0, int nT,
    char* smem, f32x4 acc[4][4])
{
  u16* Ab = (u16*)smem;               // [2][128*64]
  u16* Bb = (u16*)(smem + 32768);     // [2][128*64]
  const int tid = threadIdx.x, w = tid >> 6, l = tid & 63;
  const int wr = w >> 1, wc = w & 1;
  const int frow = l & 15, fko = l >> 4;
  const int srow = l >> 3;
  const int scol = ((l & 7) * 8) ^ (((l >> 3) & 7) << 3);

  const u16* gA = A + (size_t)(m0 + w * 32 + srow) * lda + scol;
  const u16* gB = B + (size_t)(n0 + w * 32 + srow) * ldb + scol;

  auto stageA = [&](int t) {
    if (t >= nT) return;
    const u16* s = gA + t * 64;
    u16* d = Ab + (t & 1) * 8192 + w * 2048;
    gload_lds16(s, d);
    gload_lds16(s + (size_t)8 * lda, d + 512);
    gload_lds16(s + (size_t)16 * lda, d + 1024);
    gload_lds16(s + (size_t)24 * lda, d + 1536);
  };
  auto stageB = [&](int t) {
    if (t >= nT) return;
    const u16* s = gB + t * 64;
    u16* d = Bb + (t & 1) * 8192 + w * 2048;
    gload_lds16(s, d);
    gload_lds16(s + (size_t)8 * ldb, d + 512);
    gload_lds16(s + (size_t)16 * ldb, d + 1024);
    gload_lds16(s + (size_t)24 * ldb, d + 1536);
  };

#define AOFF(mf, ks) SWZ2(((wr * 64 + (mf) * 16 + frow) * 128 + (ks) * 64 + fko * 16))
#define BOFF(nf, ks) SWZ2(((wc * 64 + (nf) * 16 + frow) * 128 + (ks) * 64 + fko * 16))

  bf16x8 s0A[4][2], s0B[4][2], s1A[4][2], s1B[4][2];

#define RD(S, T) do {                                                         \
    const char* Ab_ = (const char*)Ab + ((T) & 1) * 16384;                    \
    const char* Bb_ = (const char*)Bb + ((T) & 1) * 16384;                    \
    _Pragma("unroll") for (int nf = 0; nf < 4; ++nf)                          \
    _Pragma("unroll") for (int ks = 0; ks < 2; ++ks)                          \
        S##B[nf][ks] = *(const bf16x8*)(Bb_ + BOFF(nf, ks));                  \
    _Pragma("unroll") for (int mf = 0; mf < 4; ++mf)                          \
    _Pragma("unroll") for (int ks = 0; ks < 2; ++ks)                          \
        S##A[mf][ks] = *(const bf16x8*)(Ab_ + AOFF(mf, ks));                  \
  } while (0)

#define MM(S) do {                                                            \
    __builtin_amdgcn_s_setprio(1);                                            \
    _Pragma("unroll") for (int ks = 0; ks < 2; ++ks)                          \
    _Pragma("unroll") for (int mf = 0; mf < 4; ++mf)                          \
    _Pragma("unroll") for (int nf = 0; nf < 4; ++nf)                          \
        acc[mf][nf] = __builtin_amdgcn_mfma_f32_16x16x32_bf16(                \
            S##A[mf][ks], S##B[nf][ks], acc[mf][nf], 0, 0, 0);                \
    __builtin_amdgcn_s_setprio(0);                                            \
  } while (0)

#define WIN(T, CUR, NXT) do {                                                 \
    if ((T) < nT - 2) asm volatile("s_waitcnt vmcnt(8)" ::: "memory");        \
    else              asm volatile("s_waitcnt vmcnt(0)" ::: "memory");        \
    __builtin_amdgcn_s_barrier();                                             \
    __builtin_amdgcn_sched_barrier(0);                                        \
    if ((T) + 1 < nT) RD(NXT, (T) + 1);                                       \
    MM(CUR);                                                                  \
    asm volatile("s_waitcnt lgkmcnt(0)" ::: "memory");                        \
    __builtin_amdgcn_s_barrier();                                             \
    __builtin_amdgcn_sched_barrier(0);                                        \
    stageB((T) + 3);                                                          \
    stageA((T) + 3);                                                          \
  } while (0)

  // prologue: stage tiles 0,1; read tile0 frags; then stage tile2 (buf0
  // safe: reads(0) drained by lgkmcnt(0)+barrier).
  stageB(0); stageA(0); stageB(1); stageA(1);
  asm volatile("s_waitcnt vmcnt(8)" ::: "memory");
  __builtin_amdgcn_s_barrier();
  RD(s0, 0);
  asm volatile("s_waitcnt lgkmcnt(0)" ::: "memory");
  __builtin_amdgcn_s_barrier();
  __builtin_amdgcn_sched_barrier(0);
  stageB(2); stageA(2);

#pragma unroll 1
  for (int t = 0; t < nT; t += 2) {
    WIN(t, s0, s1);
    WIN(t + 1, s1, s0);
  }
#undef WIN
#undef MM
#undef RD
#undef AOFF
#undef BOFF
}

#define ACC_ZERO4(acc)                                  \
  _Pragma("unroll") for (int m_ = 0; m_ < 4; ++m_)      \
  _Pragma("unroll") for (int n_ = 0; n_ < 4; ++n_)      \
      acc[m_][n_] = (f32x4){0.f, 0.f, 0.f, 0.f};

// ---------------------------------------------------------------------------
// cvt: 8 elems/thread, bf16x8 16B stores
__global__ void __launch_bounds__(256) k_cvt_all(
    const float* __restrict__ x, const float* __restrict__ Wk,
    const float* __restrict__ Wq, const float* __restrict__ Wv,
    u16* __restrict__ xb, u16* __restrict__ wb)
{
  const int NX8 = (NBATCH * TSEQ * CDIM) / 8;   // 1,048,576
  const int NW8 = (CDIM * CDIM) / 8;            // 131,072
  int g = blockIdx.x * 256 + threadIdx.x;
  const float* src; u16* dst; int i;
  if (g < NX8) { src = x; dst = xb; i = g; }
  else {
    int g2 = g - NX8;
    int w = g2 / NW8; i = g2 - w * NW8;
    src = (w == 0) ? Wk : (w == 1) ? Wq : Wv;
    dst = wb + (size_t)w * CDIM * CDIM;
  }
  float4 v0 = ((const float4*)src)[2 * i];
  float4 v1 = ((const float4*)src)[2 * i + 1];
  u16x8 o;
  o[0] = f2bf(v0.x); o[1] = f2bf(v0.y); o[2] = f2bf(v0.z); o[3] = f2bf(v0.w);
  o[4] = f2bf(v1.x); o[5] = f2bf(v1.y); o[6] = f2bf(v1.z); o[7] = f2bf(v1.w);
  *(u16x8*)(dst + (size_t)8 * i) = o;
}

// ---------------------------------------------------------------------------
// QKV: A = xb [8192][1024], B = wb [3072][1024]. 1536 blocks = 8 XCD x 192.
// z==0/1 (K,Q): LDS-repacked coalesced row-major writes (bf16x8).
// z==2 (V): transpose C-tile via LDS, write Vt[b][c][t] directly.
__global__ void __launch_bounds__(256, 2) k_gemm_qkv_t(
    const u16* __restrict__ xb, const u16* __restrict__ wb,
    u16* __restrict__ kb, u16* __restrict__ qb, u16* __restrict__ vt)
{
  extern __shared__ char smem[];
  const int id = blockIdx.x;
  const int xcd = id & 7, loc = id >> 3;
  const int mt = xcd * 8 + (loc & 7);        // 0..63
  const int nt = loc >> 3;                   // 0..23
  const int m0 = mt * 128, n0g = nt * 128;

  f32x4 acc[4][4];
  ACC_ZERO4(acc);
  gemm128(xb, wb, CDIM, CDIM, m0, n0g, 16, smem, acc);

  const int tid = threadIdx.x, w = tid >> 6, l = tid & 63;
  const int wr = w >> 1, wc = w & 1;
  const int frow = l & 15, fko = l >> 4;
  const int z = n0g >> 10;
  u16* tile = (u16*)smem;  // [128][136] u16 (16B-aligned rows)
  __syncthreads();          // fence: gemm LDS fully dead on all waves
  if (z < 2) {
    u16* outp = (z == 0) ? kb : qb;
    const float scale = (z == 1) ? 0.03125f : 1.0f;
#pragma unroll
    for (int mf = 0; mf < 4; ++mf)
#pragma unroll
      for (int nf = 0; nf < 4; ++nf) {
        const int rl = wr * 64 + mf * 16 + fko * 4;
        const int cl = wc * 64 + nf * 16 + frow;
#pragma unroll
        for (int j = 0; j < 4; ++j)
          tile[(rl + j) * 136 + cl] = f2bf(acc[mf][nf][j] * scale);
      }
    __syncthreads();
    u16* dst = outp + (size_t)m0 * CDIM + (n0g & 1023);
#pragma unroll
    for (int it = 0; it < 8; ++it) {
      const int idx = it * 256 + tid;      // 0..2047
      const int r = idx >> 4, ch = idx & 15;
      *(bf16x8*)(dst + (size_t)r * CDIM + ch * 8) =
          *(const bf16x8*)(tile + r * 136 + ch * 8);
    }
  } else {
    // V-transpose epilogue: tile[c][r]; coalesced b128 writes to Vt.
#pragma unroll
    for (int mf = 0; mf < 4; ++mf)
#pragma unroll
      for (int nf = 0; nf < 4; ++nf) {
        const int cl = wc * 64 + nf * 16 + frow;
        const int rl = wr * 64 + mf * 16 + fko * 4;
#pragma unroll
        for (int j = 0; j < 4; ++j)
          tile[cl * 136 + rl + j] = f2bf(acc[mf][nf][j]);
      }
    __syncthreads();
    const int b = m0 >> 11, t0 = m0 & 2047;
    const int c0g = n0g - 2048;
    u16* dst = vt + ((size_t)b * CDIM + c0g) * TSEQ + t0;
#pragma unroll
    for (int it = 0; it < 8; ++it) {
      const int idx = it * 256 + tid;      // 0..2047
      const int c = idx >> 4, ch = idx & 15;
      *(bf16x8*)(dst + (size_t)c * TSEQ + ch * 8) =
          *(const bf16x8*)(tile + c * 136 + ch * 8);
    }
  }
}

// ---------------------------------------------------------------------------
// Scores: S = Q K^T -> P_unnorm = exp(S) bf16 (max-free) + rowsum partials.
// 544 blocks = 8 XCD x 68; per-batch 16x16 lower triangle of 128 tiles.
__global__ void __launch_bounds__(256, 2) k_gemm_scores_t(
    const u16* __restrict__ qb, const u16* __restrict__ kb,
    u16* __restrict__ pb, float* __restrict__ rs)
{
  extern __shared__ char smem[];
  const int id = blockIdx.x;
  const int sw = (id & 7) * 68 + (id >> 3);
  const int b = sw / 136;
  const int wq = sw - b * 136;
  int y = (int)((sqrtf(8.f * wq + 1.f) - 1.f) * 0.5f);
  while ((y + 1) * (y + 2) / 2 <= wq) ++y;
  while (y * (y + 1) / 2 > wq) --y;
  const int xt = wq - y * (y + 1) / 2;
  const int m0 = y * 128, n0 = xt * 128;

  const u16* A = qb + (size_t)b * TSEQ * CDIM;
  const u16* B = kb + (size_t)b * TSEQ * CDIM;
  u16* P = pb + (size_t)b * TSEQ * TSEQ;

  f32x4 acc[4][4];
  ACC_ZERO4(acc);
  gemm128(A, B, CDIM, CDIM, m0, n0, 16, smem, acc);

  const int tid = threadIdx.x, w = tid >> 6, l = tid & 63;
  const int wr = w >> 1, wc = w & 1;
  const int frow = l & 15, fko = l >> 4;
  u16* tile = (u16*)smem;                     // [128][136] u16
  float* rowpart = (float*)(smem + 34816);    // [128][2] f32

  __syncthreads();  // fence: gemm LDS fully dead on all waves
#pragma unroll
  for (int mf = 0; mf < 4; ++mf) {
#pragma unroll
    for (int j = 0; j < 4; ++j) {
      const int rloc = wr * 64 + mf * 16 + fko * 4 + j;
      const int rglob = m0 + rloc;
      float p4 = 0.f;
#pragma unroll
      for (int nf = 0; nf < 4; ++nf) {
        const int cl = wc * 64 + nf * 16 + frow;
        const int c = n0 + cl;
        float e = (c <= rglob) ? __expf(acc[mf][nf][j]) : 0.f;
        p4 += e;
        tile[rloc * 136 + cl] = f2bf(e);
      }
#pragma unroll
      for (int d = 1; d < 16; d <<= 1) p4 += __shfl_xor(p4, d);
      if (frow == 0) rowpart[rloc * 2 + wc] = p4;
    }
  }
  __syncthreads();
  u16* dst = P + (size_t)m0 * TSEQ + n0;
#pragma unroll
  for (int it = 0; it < 8; ++it) {
    const int idx = it * 256 + tid;          // 0..2047
    const int r = idx >> 4, ch = idx & 15;
    *(bf16x8*)(dst + (size_t)r * TSEQ + ch * 8) =
        *(const bf16x8*)(tile + r * 136 + ch * 8);
  }
  if (tid < 128)
    rs[((size_t)b * 16 + xt) * TSEQ + m0 + tid] =
        rowpart[tid * 2] + rowpart[tid * 2 + 1];
}

// ---------------------------------------------------------------------------
// O = (P_unnorm @ V) * inv_rowsum; causal K-extent nT = 2*(mt+1).
// inv computed inline from rs. 512 blocks = 8 XCD x 64.
// Load-balance: loc and loc+32 carry complementary mt (sum 15).
__global__ void __launch_bounds__(256, 2) k_gemm_pv_t(
    const u16* __restrict__ pb, const u16* __restrict__ vt,
    const float* __restrict__ rs, float* __restrict__ out)
{
  extern __shared__ char smem[];
  const int id = blockIdx.x;
  const int n = id & 7, loc = id >> 3;   // loc 0..63
  int b, mt;
  if (loc < 32) { mt = 15 - (loc & 15); b = loc >> 4; }
  else          { mt = loc & 15;        b = 2 + ((loc - 32) >> 4); }
  const int m0 = mt * 128, n0 = n * 128;
  const int nT = 2 * (mt + 1);

  const u16* A = pb + (size_t)b * TSEQ * TSEQ;
  const u16* B = vt + (size_t)b * CDIM * TSEQ;
  float* O = out + (size_t)b * TSEQ * CDIM;

  f32x4 acc[4][4];
  ACC_ZERO4(acc);
  gemm128(A, B, TSEQ, TSEQ, m0, n0, nT, smem, acc);

  const int tid = threadIdx.x, w = tid >> 6, l = tid & 63;
  const int wr = w >> 1, wc = w & 1;
  const int frow = l & 15, fko = l >> 4;

  // inline inv_rowsum for this block's 128 rows
  __syncthreads();
  float* sinv = (float*)smem;  // [128]
  if (tid < 128) {
    float s = 0.f;
    const float* p = rs + (size_t)b * 16 * TSEQ + m0 + tid;
    for (int x = 0; x <= mt; ++x) s += p[(size_t)x * TSEQ];
    sinv[tid] = 1.f / s;
  }
  __syncthreads();

#pragma unroll
  for (int mf = 0; mf < 4; ++mf) {
    const int rloc = wr * 64 + mf * 16 + fko * 4;
    const int r = m0 + rloc;
    const float4 iv = *(const float4*)&sinv[rloc];
    const float ivj[4] = {iv.x, iv.y, iv.z, iv.w};
#pragma unroll
    for (int nf = 0; nf < 4; ++nf) {
      const int c = n0 + wc * 64 + nf * 16 + frow;
#pragma unroll
      for (int j = 0; j < 4; ++j)
        O[(size_t)(r + j) * CDIM + c] = acc[mf][nf][j] * ivj[j];
    }
  }
}

// ---------------------------------------------------------------------------
extern "C" void kernel_launch(void* const* d_in, const int* in_sizes, int n_in,
                              void* d_out, int out_size, void* d_ws, size_t ws_size,
                              hipStream_t stream) {
  const float* x  = (const float*)d_in[0];
  const float* Wk = (const float*)d_in[1];
  const float* Wq = (const float*)d_in[2];
  const float* Wv = (const float*)d_in[3];
  float* out = (float*)d_out;

  const size_t M = (size_t)NBATCH * TSEQ;

  size_t off = 0;
  auto alloc = [&](size_t bytes) {
    void* p = (char*)d_ws + off;
    off += (bytes + 255) & ~(size_t)255;
    return p;
  };
  u16* xb = (u16*)alloc(M * CDIM * 2);                 // x bf16 (live all of qkv)
  u16* wb = (u16*)alloc(3ull * CDIM * CDIM * 2);       // Wk|Wq|Wv bf16
  u16* qb = (u16*)alloc(M * CDIM * 2);                 // Q (pre-scaled)
  u16* kb = (u16*)alloc(M * CDIM * 2);                 // K
  u16* vt = (u16*)alloc(M * CDIM * 2);                 // Vt [B][C][T]
  u16* pbuf = (u16*)alloc((size_t)NBATCH * TSEQ * TSEQ * 2);   // P_unnorm bf16
  float* rs = (float*)alloc((size_t)NBATCH * 16 * TSEQ * 4);   // rowsum partials
  if (off > ws_size) {
    fprintf(stderr, "kernel_launch: ws too small: need %zu, have %zu\n", off, ws_size);
    return;
  }

  const int NX8 = (NBATCH * TSEQ * CDIM) / 8;
  const int NW8 = (CDIM * CDIM) / 8;
  const int cvtBlocks = (NX8 + 3 * NW8) / 256;

  static_cast<void>(hipFuncSetAttribute(
      reinterpret_cast<const void*>(k_gemm_qkv_t),
      hipFuncAttributeMaxDynamicSharedMemorySize, 65536));
  static_cast<void>(hipFuncSetAttribute(
      reinterpret_cast<const void*>(k_gemm_scores_t),
      hipFuncAttributeMaxDynamicSharedMemorySize, 65536));
  static_cast<void>(hipFuncSetAttribute(
      reinterpret_cast<const void*>(k_gemm_pv_t),
      hipFuncAttributeMaxDynamicSharedMemorySize, 65536));

  k_cvt_all<<<cvtBlocks, 256, 0, stream>>>(x, Wk, Wq, Wv, xb, wb);
  k_gemm_qkv_t<<<1536, 256, 65536, stream>>>(xb, wb, kb, qb, vt);
  k_gemm_scores_t<<<544, 256, 65536, stream>>>(qb, kb, pbuf, rs);
  k_gemm_pv_t<<<512, 256, 65536, stream>>>(pbuf, vt, rs, out);
}